// Round 1
// baseline (366.518 us; speedup 1.0000x reference)
//
#include <hip/hip_runtime.h>

#define HD 128

typedef __attribute__((ext_vector_type(8))) short short8;   // 8 bf16
typedef __attribute__((ext_vector_type(4))) float floatx4;  // MFMA accumulator
typedef __attribute__((ext_vector_type(2))) unsigned short ushort2v;

typedef unsigned short ushort_t;
typedef unsigned int uint_t;

// ---------------------------------------------------------------- helpers ----
__device__ __forceinline__ ushort_t f2b(float f) {          // fp32 -> bf16 RNE
    union { float f; uint_t u; } v; v.f = f;
    uint_t r = v.u + 0x7fff + ((v.u >> 16) & 1);
    return (ushort_t)(r >> 16);
}
__device__ __forceinline__ short8 cvt8(const float* __restrict__ p) {
    float4 u = *(const float4*)p, v = *(const float4*)(p + 4);
    short8 r;
    r[0] = (short)f2b(u.x); r[1] = (short)f2b(u.y); r[2] = (short)f2b(u.z); r[3] = (short)f2b(u.w);
    r[4] = (short)f2b(v.x); r[5] = (short)f2b(v.y); r[6] = (short)f2b(v.z); r[7] = (short)f2b(v.w);
    return r;
}
// packed bf16 max: valid because m = relu(..) >= 0, so IEEE order == u16 order.
__device__ __forceinline__ uint_t pkmax(uint_t a, uint_t b) {
    return __builtin_bit_cast(uint_t,
        __builtin_elementwise_max(__builtin_bit_cast(ushort2v, a),
                                  __builtin_bit_cast(ushort2v, b)));
}

// ------------------------------------------------------------------ prep -----
// [0,nbR): rowptr (rp[i] = lower_bound(dst,i)); rest: W-pack to frag order.
// Frag map (identical for A- and B-operand): lane&15 -> non-K dim, quad*8+j -> K.
__global__ __launch_bounds__(256) void k_prep(const int* __restrict__ dst, int E,
                                              int* __restrict__ rp, int N,
                                              const float* W0, const float* W1,
                                              const float* W2, const float* W3,
                                              const float* W4, const float* W5,
                                              ushort_t* __restrict__ Wpk, int nbR) {
    int b = blockIdx.x;
    if (b < nbR) {
        int i = b * 256 + threadIdx.x;
        if (i > N) return;
        int lo = 0, hi = E;
        while (lo < hi) {
            int mid = (lo + hi) >> 1;
            if (dst[mid] < i) lo = mid + 1; else hi = mid;
        }
        rp[i] = lo;
    } else {
        int bb = b - nbR;
        const float* Ws[6] = {W0, W1, W2, W3, W4, W5};
        int mat = bb >> 6;
        int o = ((bb & 63) << 8) + threadIdx.x;
        int j = o & 7, l = (o >> 3) & 63, s = (o >> 9) & 3, t = o >> 11;
        int k = s * 32 + ((l >> 4) & 3) * 8 + j;
        int n = t * 16 + (l & 15);
        Wpk[(size_t)mat * 16384 + o] = f2b(Ws[mat][k * HD + n]);
    }
}

// ---------------------------------------------------------- W -> LDS stage ---
__device__ __forceinline__ void stage_w(const ushort_t* __restrict__ g,
                                        ushort_t* l, int tid) {
#pragma unroll
    for (int i = 0; i < 8; ++i) {
        int off = i * 2048 + tid * 8;
        *(short8*)&l[off] = *(const short8*)&g[off];
    }
}

// --------------------------------------------------------------- epilogue ----
// D = mfma(Wfrag, hfrag): lane&15 = h-row, quad*4+reg = output col within tile.
__device__ __forceinline__ void store_bf16(ushort_t* __restrict__ m, int row,
                                           int colbase, const floatx4& acc,
                                           const float4& bv, bool relu, int N) {
    if (row >= N) return;
    float v0 = acc[0] + bv.x, v1 = acc[1] + bv.y, v2 = acc[2] + bv.z, v3 = acc[3] + bv.w;
    if (relu) { v0 = fmaxf(v0, 0.f); v1 = fmaxf(v1, 0.f); v2 = fmaxf(v2, 0.f); v3 = fmaxf(v3, 0.f); }
    uint2 o; o.x = (uint_t)f2b(v0) | ((uint_t)f2b(v1) << 16);
    o.y = (uint_t)f2b(v2) | ((uint_t)f2b(v3) << 16);
    *(uint2*)&m[(size_t)row * HD + colbase] = o;
}

// m is stored col-group-major: [8 groups][N rows][16 cols] bf16, so each group's
// slice is a contiguous 1.6 MB (L2-resident per XCD during segmax).
__device__ __forceinline__ void store_m(ushort_t* __restrict__ m, int row,
                                        int colbase, const floatx4& acc,
                                        const float4& bv, int N) {
    if (row >= N) return;
    float v0 = fmaxf(acc[0] + bv.x, 0.f), v1 = fmaxf(acc[1] + bv.y, 0.f);
    float v2 = fmaxf(acc[2] + bv.z, 0.f), v3 = fmaxf(acc[3] + bv.w, 0.f);
    uint2 o; o.x = (uint_t)f2b(v0) | ((uint_t)f2b(v1) << 16);
    o.y = (uint_t)f2b(v2) | ((uint_t)f2b(v3) << 16);
    size_t addr = (size_t)(colbase >> 4) * ((size_t)N * 16)
                + (size_t)row * 16 + (colbase & 15);
    *(uint2*)&m[addr] = o;
}

// ------------------------------------------------------ gather + pool GEMM ---
// h0 = bf16(emb[ids]);  m = relu(h0 @ Wp + b).  A loads overlap W staging.
__global__ __launch_bounds__(256) void k_gather_pool(const int* __restrict__ ids,
                                                     const float* __restrict__ emb,
                                                     const ushort_t* __restrict__ Wpk,
                                                     const float* __restrict__ bias,
                                                     ushort_t* __restrict__ h0,
                                                     ushort_t* __restrict__ m, int N) {
    __shared__ ushort_t Wl[16384];
    int wave = blockIdx.x * 4 + (threadIdx.x >> 6);
    int row0 = wave * 32;
    int l = threadIdx.x & 63;
    int ar0 = row0 + (l & 15); if (ar0 >= N) ar0 = N - 1;
    int ar1 = ar0 + 16;        if (ar1 >= N) ar1 = N - 1;
    int ac = (l >> 4) * 8;
    int id0 = ids[ar0], id1 = ids[ar1];
    short8 a0[4], a1[4];
#pragma unroll
    for (int s = 0; s < 4; ++s) {
        a0[s] = cvt8(&emb[(size_t)id0 * HD + s * 32 + ac]);
        a1[s] = cvt8(&emb[(size_t)id1 * HD + s * 32 + ac]);
    }
    stage_w(Wpk, Wl, threadIdx.x);
    __syncthreads();
    if (row0 >= N) return;
#pragma unroll
    for (int s = 0; s < 4; ++s) {
        *(short8*)&h0[(size_t)ar0 * HD + s * 32 + ac] = a0[s];
        *(short8*)&h0[(size_t)ar1 * HD + s * 32 + ac] = a1[s];
    }
    int g0 = row0 + (l & 15), g1 = g0 + 16;
    int cb0 = ((l >> 4) & 3) * 4;
#pragma unroll
    for (int t = 0; t < 8; ++t) {
        floatx4 acc0 = {0.f, 0.f, 0.f, 0.f};
        floatx4 acc1 = {0.f, 0.f, 0.f, 0.f};
#pragma unroll
        for (int s = 0; s < 4; ++s) {
            short8 w = *(const short8*)&Wl[(t * 4 + s) * 512 + l * 8];
            acc0 = __builtin_amdgcn_mfma_f32_16x16x32_bf16(w, a0[s], acc0, 0, 0, 0);
            acc1 = __builtin_amdgcn_mfma_f32_16x16x32_bf16(w, a1[s], acc1, 0, 0, 0);
        }
        int cb = t * 16 + cb0;
        float4 bv = *(const float4*)&bias[cb];
        store_m(m, g0, cb, acc0, bv, N);
        store_m(m, g1, cb, acc1, bv, N);
    }
}

// ----------------------------------------------------------- pool GEMM only --
__global__ __launch_bounds__(256) void k_pool(const ushort_t* __restrict__ h,
                                              const ushort_t* __restrict__ Wpk,
                                              const float* __restrict__ bias,
                                              ushort_t* __restrict__ m, int N) {
    __shared__ ushort_t Wl[16384];
    int wave = blockIdx.x * 4 + (threadIdx.x >> 6);
    int row0 = wave * 32;
    int l = threadIdx.x & 63;
    int ar0 = row0 + (l & 15); if (ar0 >= N) ar0 = N - 1;
    int ar1 = ar0 + 16;        if (ar1 >= N) ar1 = N - 1;
    int ac = (l >> 4) * 8;
    short8 a0[4], a1[4];
#pragma unroll
    for (int s = 0; s < 4; ++s) {
        a0[s] = *(const short8*)&h[(size_t)ar0 * HD + s * 32 + ac];
        a1[s] = *(const short8*)&h[(size_t)ar1 * HD + s * 32 + ac];
    }
    stage_w(Wpk, Wl, threadIdx.x);
    __syncthreads();
    if (row0 >= N) return;
    int g0 = row0 + (l & 15), g1 = g0 + 16;
    int cb0 = ((l >> 4) & 3) * 4;
#pragma unroll
    for (int t = 0; t < 8; ++t) {
        floatx4 acc0 = {0.f, 0.f, 0.f, 0.f};
        floatx4 acc1 = {0.f, 0.f, 0.f, 0.f};
#pragma unroll
        for (int s = 0; s < 4; ++s) {
            short8 w = *(const short8*)&Wl[(t * 4 + s) * 512 + l * 8];
            acc0 = __builtin_amdgcn_mfma_f32_16x16x32_bf16(w, a0[s], acc0, 0, 0, 0);
            acc1 = __builtin_amdgcn_mfma_f32_16x16x32_bf16(w, a1[s], acc1, 0, 0, 0);
        }
        int cb = t * 16 + cb0;
        float4 bv = *(const float4*)&bias[cb];
        store_m(m, g0, cb, acc0, bv, N);
        store_m(m, g1, cb, acc1, bv, N);
    }
}

// ---------------------------------------------------------------- segmax -----
// Col-group-split: blockIdx&7 selects a 16-col group (contiguous 1.6 MB slice
// of m) -> with round-robin block->XCD dispatch, each XCD gathers from its own
// L2-resident slice. 8 edge slots x 8 lanes (one u32 = 2 bf16 per lane).
// Packed u16 max is exact for the nonneg relu outputs. src loads / agg stores
// are non-temporal so streaming traffic doesn't evict the slice.
__global__ __launch_bounds__(256) void k_segmax(const ushort_t* __restrict__ m,
                                                const int* __restrict__ src,
                                                const int* __restrict__ rp,
                                                ushort_t* __restrict__ agg, int N) {
    int cg = blockIdx.x & 7;
    int l = threadIdx.x & 63;
    int slot = l >> 3;                 // 0..7 edge slot
    int c = l & 7;                     // u32 word within the 16-col group
    int node0 = ((blockIdx.x >> 3) * 4 + (threadIdx.x >> 6)) * 4;
    const uint_t* __restrict__ mg = (const uint_t*)m + (size_t)cg * ((size_t)N * 8);
    uint_t* __restrict__ aggw = (uint_t*)agg;
#pragma unroll 1
    for (int nn = 0; nn < 4; ++nn) {
        int node = node0 + nn;
        if (node >= N) return;
        int beg = rp[node], end = rp[node + 1];
        uint_t a = 0u, b = 0u;
        for (int base = beg; base < end; base += 64) {
            int nb = end - base; if (nb > 64) nb = 64;
            int si = base + l; if (si > end - 1) si = end - 1;
            int sv = __builtin_nontemporal_load(&src[si]);   // coalesced 64 idx
            for (int o = 0; o < nb; o += 16) {
                int last = nb - 1;
                int i0 = o + slot;     if (i0 > last) i0 = last;
                int i1 = o + 8 + slot; if (i1 > last) i1 = last;
                int s0 = __shfl(sv, i0), s1 = __shfl(sv, i1);
                uint_t p0 = mg[(size_t)s0 * 8 + c];
                uint_t p1 = mg[(size_t)s1 * 8 + c];
                a = pkmax(a, p0);
                b = pkmax(b, p1);
            }
        }
        a = pkmax(a, b);
        a = pkmax(a, (uint_t)__shfl_xor((int)a, 8));
        a = pkmax(a, (uint_t)__shfl_xor((int)a, 16));
        a = pkmax(a, (uint_t)__shfl_xor((int)a, 32));
        if (slot == 0)                 // agg stays row-major for k_dual
            __builtin_nontemporal_store(a, &aggw[(size_t)node * 64 + cg * 8 + c]);
    }
}

// ----------------------------------------------------------- dual GEMM -------
// out = h @ Wself + agg @ Wneigh + b; A/agg loads overlap W staging.
template <bool F32OUT>
__global__ __launch_bounds__(256) void k_dual(const ushort_t* __restrict__ h,
                                              const ushort_t* __restrict__ agg,
                                              const ushort_t* __restrict__ WsPk,
                                              const ushort_t* __restrict__ WnPk,
                                              const float* __restrict__ bias,
                                              void* __restrict__ outp, int N) {
    __shared__ ushort_t Wl[32768];                       // Ws | Wn
    int wave = blockIdx.x * 4 + (threadIdx.x >> 6);
    int row0 = wave * 32;
    int l = threadIdx.x & 63;
    int ar0 = row0 + (l & 15); if (ar0 >= N) ar0 = N - 1;
    int ar1 = ar0 + 16;        if (ar1 >= N) ar1 = N - 1;
    int ac = (l >> 4) * 8;
    short8 ah0[4], ah1[4], ag0[4], ag1[4];
#pragma unroll
    for (int s = 0; s < 4; ++s) {
        ah0[s] = *(const short8*)&h[(size_t)ar0 * HD + s * 32 + ac];
        ah1[s] = *(const short8*)&h[(size_t)ar1 * HD + s * 32 + ac];
        ag0[s] = *(const short8*)&agg[(size_t)ar0 * HD + s * 32 + ac];
        ag1[s] = *(const short8*)&agg[(size_t)ar1 * HD + s * 32 + ac];
    }
    stage_w(WsPk, Wl, threadIdx.x);
    stage_w(WnPk, Wl + 16384, threadIdx.x);
    __syncthreads();
    if (row0 >= N) return;
    int g0 = row0 + (l & 15), g1 = g0 + 16;
    int cb0 = ((l >> 4) & 3) * 4;
#pragma unroll
    for (int t = 0; t < 8; ++t) {
        floatx4 acc0 = {0.f, 0.f, 0.f, 0.f};
        floatx4 acc1 = {0.f, 0.f, 0.f, 0.f};
#pragma unroll
        for (int s = 0; s < 4; ++s) {
            short8 ws = *(const short8*)&Wl[(t * 4 + s) * 512 + l * 8];
            acc0 = __builtin_amdgcn_mfma_f32_16x16x32_bf16(ws, ah0[s], acc0, 0, 0, 0);
            acc1 = __builtin_amdgcn_mfma_f32_16x16x32_bf16(ws, ah1[s], acc1, 0, 0, 0);
        }
#pragma unroll
        for (int s = 0; s < 4; ++s) {
            short8 wn = *(const short8*)&Wl[16384 + (t * 4 + s) * 512 + l * 8];
            acc0 = __builtin_amdgcn_mfma_f32_16x16x32_bf16(wn, ag0[s], acc0, 0, 0, 0);
            acc1 = __builtin_amdgcn_mfma_f32_16x16x32_bf16(wn, ag1[s], acc1, 0, 0, 0);
        }
        int cb = t * 16 + cb0;
        float4 bv = *(const float4*)&bias[cb];
        if (F32OUT) {
            float* out = (float*)outp;
            if (g0 < N) {
                float4 v = make_float4(acc0[0] + bv.x, acc0[1] + bv.y,
                                       acc0[2] + bv.z, acc0[3] + bv.w);
                *(float4*)&out[(size_t)g0 * HD + cb] = v;
            }
            if (g1 < N) {
                float4 v = make_float4(acc1[0] + bv.x, acc1[1] + bv.y,
                                       acc1[2] + bv.z, acc1[3] + bv.w);
                *(float4*)&out[(size_t)g1 * HD + cb] = v;
            }
        } else {
            ushort_t* out = (ushort_t*)outp;
            store_bf16(out, g0, cb, acc0, bv, false, N);
            store_bf16(out, g1, cb, acc1, bv, false, N);
        }
    }
}

// ---------------------------------------------------------------- launch -----
extern "C" void kernel_launch(void* const* d_in, const int* in_sizes, int n_in,
                              void* d_out, int out_size, void* d_ws, size_t ws_size,
                              hipStream_t stream) {
    const int*   node_ids = (const int*)d_in[0];
    const int*   src      = (const int*)d_in[1];
    const int*   dst      = (const int*)d_in[2];
    const float* emb      = (const float*)d_in[3];
    const float* Wp1      = (const float*)d_in[4];
    const float* bp1      = (const float*)d_in[5];
    const float* Ws1      = (const float*)d_in[6];
    const float* Wn1      = (const float*)d_in[7];
    const float* b1       = (const float*)d_in[8];
    const float* Wp2      = (const float*)d_in[9];
    const float* bp2      = (const float*)d_in[10];
    const float* Ws2      = (const float*)d_in[11];
    const float* Wn2      = (const float*)d_in[12];
    const float* b2       = (const float*)d_in[13];
    float* out = (float*)d_out;

    const int N = in_sizes[0];
    const int E = in_sizes[1];

    char* ws = (char*)d_ws;
    int* rp = (int*)ws;
    size_t off = (((size_t)(N + 1) * 4) + 255) & ~(size_t)255;
    ushort_t* Wpk  = (ushort_t*)(ws + off);              // 6 x 128x128 bf16
    ushort_t* h0   = Wpk + 6 * 16384;
    ushort_t* h1   = h0 + (size_t)N * HD;
    ushort_t* bufM = h1 + (size_t)N * HD;                // col-group-major [8][N][16]
    ushort_t* bufA = bufM + (size_t)N * HD;

    const int nbR = (N + 1 + 255) / 256;
    const int nbP = 6 * 64;
    const int nb_gemm = (N + 127) / 128;                 // 4 waves x 32 rows
    const int nb_seg  = ((N + 15) / 16) * 8;             // 8 col-groups x node-blocks

    k_prep<<<nbR + nbP, 256, 0, stream>>>(dst, E, rp, N,
                                          Wp1, Ws1, Wn1, Wp2, Ws2, Wn2, Wpk, nbR);

    const ushort_t* Wp1k = Wpk;
    const ushort_t* Ws1k = Wpk + 16384;
    const ushort_t* Wn1k = Wpk + 2 * 16384;
    const ushort_t* Wp2k = Wpk + 3 * 16384;
    const ushort_t* Ws2k = Wpk + 4 * 16384;
    const ushort_t* Wn2k = Wpk + 5 * 16384;

    // layer 1
    k_gather_pool<<<nb_gemm, 256, 0, stream>>>(node_ids, emb, Wp1k, bp1, h0, bufM, N);
    k_segmax<<<nb_seg, 256, 0, stream>>>(bufM, src, rp, bufA, N);
    k_dual<false><<<nb_gemm, 256, 0, stream>>>(h0, bufA, Ws1k, Wn1k, b1, h1, N);
    // layer 2
    k_pool<<<nb_gemm, 256, 0, stream>>>(h1, Wp2k, bp2, bufM, N);
    k_segmax<<<nb_seg, 256, 0, stream>>>(bufM, src, rp, bufA, N);
    k_dual<true><<<nb_gemm, 256, 0, stream>>>(h1, bufA, Ws2k, Wn2k, b2, out, N);
}

// Round 3
// 255.034 us; speedup vs baseline: 1.4371x; 1.4371x over previous
//
#include <hip/hip_runtime.h>

#define HD 128

typedef __attribute__((ext_vector_type(8))) short short8;   // 8 bf16
typedef __attribute__((ext_vector_type(4))) float floatx4;  // MFMA accumulator
typedef __attribute__((ext_vector_type(2))) unsigned short ushort2v;
typedef __attribute__((ext_vector_type(4))) unsigned int uint4v;

typedef unsigned short ushort_t;
typedef unsigned int uint_t;

// ---------------------------------------------------------------- helpers ----
__device__ __forceinline__ ushort_t f2b(float f) {          // fp32 -> bf16 RNE
    union { float f; uint_t u; } v; v.f = f;
    uint_t r = v.u + 0x7fff + ((v.u >> 16) & 1);
    return (ushort_t)(r >> 16);
}
__device__ __forceinline__ short8 cvt8(const float* __restrict__ p) {
    float4 u = *(const float4*)p, v = *(const float4*)(p + 4);
    short8 r;
    r[0] = (short)f2b(u.x); r[1] = (short)f2b(u.y); r[2] = (short)f2b(u.z); r[3] = (short)f2b(u.w);
    r[4] = (short)f2b(v.x); r[5] = (short)f2b(v.y); r[6] = (short)f2b(v.z); r[7] = (short)f2b(v.w);
    return r;
}
// packed bf16 max: valid because m = relu(..) >= 0, so IEEE order == u16 order.
__device__ __forceinline__ uint_t pkmax(uint_t a, uint_t b) {
    return __builtin_bit_cast(uint_t,
        __builtin_elementwise_max(__builtin_bit_cast(ushort2v, a),
                                  __builtin_bit_cast(ushort2v, b)));
}

// ------------------------------------------------------------------ prep -----
// [0,nbR): rowptr (rp[i] = lower_bound(dst,i)); rest: W-pack to frag order.
// Frag map (identical for A- and B-operand): lane&15 -> non-K dim, quad*8+j -> K.
__global__ __launch_bounds__(256) void k_prep(const int* __restrict__ dst, int E,
                                              int* __restrict__ rp, int N,
                                              const float* W0, const float* W1,
                                              const float* W2, const float* W3,
                                              const float* W4, const float* W5,
                                              ushort_t* __restrict__ Wpk, int nbR) {
    int b = blockIdx.x;
    if (b < nbR) {
        int i = b * 256 + threadIdx.x;
        if (i > N) return;
        int lo = 0, hi = E;
        while (lo < hi) {
            int mid = (lo + hi) >> 1;
            if (dst[mid] < i) lo = mid + 1; else hi = mid;
        }
        rp[i] = lo;
    } else {
        int bb = b - nbR;
        const float* Ws[6] = {W0, W1, W2, W3, W4, W5};
        int mat = bb >> 6;
        int o = ((bb & 63) << 8) + threadIdx.x;
        int j = o & 7, l = (o >> 3) & 63, s = (o >> 9) & 3, t = o >> 11;
        int k = s * 32 + ((l >> 4) & 3) * 8 + j;
        int n = t * 16 + (l & 15);
        Wpk[(size_t)mat * 16384 + o] = f2b(Ws[mat][k * HD + n]);
    }
}

// ---------------------------------------------------------- W -> LDS stage ---
__device__ __forceinline__ void stage_w(const ushort_t* __restrict__ g,
                                        ushort_t* l, int tid) {
#pragma unroll
    for (int i = 0; i < 8; ++i) {
        int off = i * 2048 + tid * 8;
        *(short8*)&l[off] = *(const short8*)&g[off];
    }
}

// --------------------------------------------------------------- epilogue ----
// D = mfma(Wfrag, hfrag): lane&15 = h-row, quad*4+reg = output col within tile.
__device__ __forceinline__ void store_bf16(ushort_t* __restrict__ m, int row,
                                           int colbase, const floatx4& acc,
                                           const float4& bv, bool relu, int N) {
    if (row >= N) return;
    float v0 = acc[0] + bv.x, v1 = acc[1] + bv.y, v2 = acc[2] + bv.z, v3 = acc[3] + bv.w;
    if (relu) { v0 = fmaxf(v0, 0.f); v1 = fmaxf(v1, 0.f); v2 = fmaxf(v2, 0.f); v3 = fmaxf(v3, 0.f); }
    uint2 o; o.x = (uint_t)f2b(v0) | ((uint_t)f2b(v1) << 16);
    o.y = (uint_t)f2b(v2) | ((uint_t)f2b(v3) << 16);
    *(uint2*)&m[(size_t)row * HD + colbase] = o;
}

// m is stored col-group-major: [4 groups][N rows][32 cols] bf16.  One group's
// slice = N*64 B = 3.2 MB (fits a 4 MiB XCD L2); one row-slice = exactly one
// 64 B cache line.
__device__ __forceinline__ void store_m(ushort_t* __restrict__ m, int row,
                                        int colbase, const floatx4& acc,
                                        const float4& bv, int N) {
    if (row >= N) return;
    float v0 = fmaxf(acc[0] + bv.x, 0.f), v1 = fmaxf(acc[1] + bv.y, 0.f);
    float v2 = fmaxf(acc[2] + bv.z, 0.f), v3 = fmaxf(acc[3] + bv.w, 0.f);
    uint2 o; o.x = (uint_t)f2b(v0) | ((uint_t)f2b(v1) << 16);
    o.y = (uint_t)f2b(v2) | ((uint_t)f2b(v3) << 16);
    size_t addr = (size_t)(colbase >> 5) * ((size_t)N * 32)
                + (size_t)row * 32 + (colbase & 31);
    *(uint2*)&m[addr] = o;
}

// ------------------------------------------------------ gather + pool GEMM ---
// h0 = bf16(emb[ids]);  m = relu(h0 @ Wp + b).  A loads overlap W staging.
__global__ __launch_bounds__(256) void k_gather_pool(const int* __restrict__ ids,
                                                     const float* __restrict__ emb,
                                                     const ushort_t* __restrict__ Wpk,
                                                     const float* __restrict__ bias,
                                                     ushort_t* __restrict__ h0,
                                                     ushort_t* __restrict__ m, int N) {
    __shared__ ushort_t Wl[16384];
    int wave = blockIdx.x * 4 + (threadIdx.x >> 6);
    int row0 = wave * 32;
    int l = threadIdx.x & 63;
    int ar0 = row0 + (l & 15); if (ar0 >= N) ar0 = N - 1;
    int ar1 = ar0 + 16;        if (ar1 >= N) ar1 = N - 1;
    int ac = (l >> 4) * 8;
    int id0 = ids[ar0], id1 = ids[ar1];
    short8 a0[4], a1[4];
#pragma unroll
    for (int s = 0; s < 4; ++s) {
        a0[s] = cvt8(&emb[(size_t)id0 * HD + s * 32 + ac]);
        a1[s] = cvt8(&emb[(size_t)id1 * HD + s * 32 + ac]);
    }
    stage_w(Wpk, Wl, threadIdx.x);
    __syncthreads();
    if (row0 >= N) return;
#pragma unroll
    for (int s = 0; s < 4; ++s) {
        *(short8*)&h0[(size_t)ar0 * HD + s * 32 + ac] = a0[s];
        *(short8*)&h0[(size_t)ar1 * HD + s * 32 + ac] = a1[s];
    }
    int g0 = row0 + (l & 15), g1 = g0 + 16;
    int cb0 = ((l >> 4) & 3) * 4;
#pragma unroll
    for (int t = 0; t < 8; ++t) {
        floatx4 acc0 = {0.f, 0.f, 0.f, 0.f};
        floatx4 acc1 = {0.f, 0.f, 0.f, 0.f};
#pragma unroll
        for (int s = 0; s < 4; ++s) {
            short8 w = *(const short8*)&Wl[(t * 4 + s) * 512 + l * 8];
            acc0 = __builtin_amdgcn_mfma_f32_16x16x32_bf16(w, a0[s], acc0, 0, 0, 0);
            acc1 = __builtin_amdgcn_mfma_f32_16x16x32_bf16(w, a1[s], acc1, 0, 0, 0);
        }
        int cb = t * 16 + cb0;
        float4 bv = *(const float4*)&bias[cb];
        store_m(m, g0, cb, acc0, bv, N);
        store_m(m, g1, cb, acc1, bv, N);
    }
}

// ----------------------------------------------------------- pool GEMM only --
__global__ __launch_bounds__(256) void k_pool(const ushort_t* __restrict__ h,
                                              const ushort_t* __restrict__ Wpk,
                                              const float* __restrict__ bias,
                                              ushort_t* __restrict__ m, int N) {
    __shared__ ushort_t Wl[16384];
    int wave = blockIdx.x * 4 + (threadIdx.x >> 6);
    int row0 = wave * 32;
    int l = threadIdx.x & 63;
    int ar0 = row0 + (l & 15); if (ar0 >= N) ar0 = N - 1;
    int ar1 = ar0 + 16;        if (ar1 >= N) ar1 = N - 1;
    int ac = (l >> 4) * 8;
    short8 a0[4], a1[4];
#pragma unroll
    for (int s = 0; s < 4; ++s) {
        a0[s] = *(const short8*)&h[(size_t)ar0 * HD + s * 32 + ac];
        a1[s] = *(const short8*)&h[(size_t)ar1 * HD + s * 32 + ac];
    }
    stage_w(Wpk, Wl, threadIdx.x);
    __syncthreads();
    if (row0 >= N) return;
    int g0 = row0 + (l & 15), g1 = g0 + 16;
    int cb0 = ((l >> 4) & 3) * 4;
#pragma unroll
    for (int t = 0; t < 8; ++t) {
        floatx4 acc0 = {0.f, 0.f, 0.f, 0.f};
        floatx4 acc1 = {0.f, 0.f, 0.f, 0.f};
#pragma unroll
        for (int s = 0; s < 4; ++s) {
            short8 w = *(const short8*)&Wl[(t * 4 + s) * 512 + l * 8];
            acc0 = __builtin_amdgcn_mfma_f32_16x16x32_bf16(w, a0[s], acc0, 0, 0, 0);
            acc1 = __builtin_amdgcn_mfma_f32_16x16x32_bf16(w, a1[s], acc1, 0, 0, 0);
        }
        int cb = t * 16 + cb0;
        float4 bv = *(const float4*)&bias[cb];
        store_m(m, g0, cb, acc0, bv, N);
        store_m(m, g1, cb, acc1, bv, N);
    }
}

// ---------------------------------------------------------------- segmax -----
// 4 col-groups of 32 cols: blockIdx&3 selects a contiguous 3.2 MB slice of m;
// round-robin block->XCD dispatch pins each slice to 2 XCDs (L2-resident).
// Each edge row-slice = one 64 B line, gathered by a 4-lane quad (16 B/lane).
// 16 edge slots/wave, dual uint4v accumulators (2 gathers in flight), src loads
// for all 4 nodes hoisted (4 in flight).  Clamp duplicates are broadcasts and
// idempotent under max.  src non-temporal so the stream can't evict the slice.
__global__ __launch_bounds__(256) void k_segmax(const ushort_t* __restrict__ m,
                                                const int* __restrict__ src,
                                                const int* __restrict__ rp,
                                                ushort_t* __restrict__ agg, int N) {
    int cg = blockIdx.x & 3;
    int l = threadIdx.x & 63;
    int slot = l >> 2;                 // 0..15 edge slot
    int c = l & 3;                     // 16 B (4 u32) within the 64 B row-slice
    int node0 = ((blockIdx.x >> 2) * 4 + (threadIdx.x >> 6)) * 4;
    if (node0 >= N) return;
    const uint_t* __restrict__ mg = (const uint_t*)m + (size_t)cg * ((size_t)N * 16);
    uint_t* __restrict__ aggw = (uint_t*)agg;

    int bg[4], en[4], sv[4];
#pragma unroll
    for (int nn = 0; nn < 4; ++nn) {
        int node = node0 + nn;
        bg[nn] = (node < N) ? rp[node] : 0;
        en[nn] = (node < N) ? rp[node + 1] : 0;
    }
#pragma unroll
    for (int nn = 0; nn < 4; ++nn) {   // all 4 src loads in flight
        int si = bg[nn] + l, lim = en[nn] - 1;
        si = si > lim ? lim : si; si = si < 0 ? 0 : si;
        sv[nn] = __builtin_nontemporal_load(&src[si]);
    }
#pragma unroll
    for (int nn = 0; nn < 4; ++nn) {
        int node = node0 + nn;
        if (node >= N) continue;
        int beg = bg[nn], end = en[nn];
        uint_t a0 = 0u, a1 = 0u, a2 = 0u, a3 = 0u;
        uint_t b0 = 0u, b1 = 0u, b2 = 0u, b3 = 0u;
        int svc = sv[nn];
        for (int base = beg; base < end; base += 64) {
            int nb = end - base; if (nb > 64) nb = 64;
            int last = nb - 1;
            for (int o = 0; o < nb; o += 32) {
                int i0 = o + slot;      if (i0 > last) i0 = last;
                int i1 = o + 16 + slot; if (i1 > last) i1 = last;
                int s0 = __shfl(svc, i0), s1 = __shfl(svc, i1);
                uint4v p0 = *(const uint4v*)&mg[(size_t)s0 * 16 + c * 4];
                uint4v p1 = *(const uint4v*)&mg[(size_t)s1 * 16 + c * 4];
                a0 = pkmax(a0, p0.x); a1 = pkmax(a1, p0.y);
                a2 = pkmax(a2, p0.z); a3 = pkmax(a3, p0.w);
                b0 = pkmax(b0, p1.x); b1 = pkmax(b1, p1.y);
                b2 = pkmax(b2, p1.z); b3 = pkmax(b3, p1.w);
            }
            if (base + 64 < end) {     // rare: degree > 64
                int si = base + 64 + l, lim = end - 1;
                si = si > lim ? lim : si;
                svc = __builtin_nontemporal_load(&src[si]);
            }
        }
        a0 = pkmax(a0, b0); a1 = pkmax(a1, b1);
        a2 = pkmax(a2, b2); a3 = pkmax(a3, b3);
#pragma unroll
        for (int d = 4; d <= 32; d <<= 1) {   // reduce across 16 slots
            a0 = pkmax(a0, (uint_t)__shfl_xor((int)a0, d));
            a1 = pkmax(a1, (uint_t)__shfl_xor((int)a1, d));
            a2 = pkmax(a2, (uint_t)__shfl_xor((int)a2, d));
            a3 = pkmax(a3, (uint_t)__shfl_xor((int)a3, d));
        }
        if (slot == 0) {               // agg stays row-major for k_dual
            uint4v o; o.x = a0; o.y = a1; o.z = a2; o.w = a3;
            __builtin_nontemporal_store(o, (uint4v*)&aggw[(size_t)node * 64 + cg * 16 + c * 4]);
        }
    }
}

// ----------------------------------------------------------- dual GEMM -------
// out = h @ Wself + agg @ Wneigh + b; A/agg loads overlap W staging.
template <bool F32OUT>
__global__ __launch_bounds__(256) void k_dual(const ushort_t* __restrict__ h,
                                              const ushort_t* __restrict__ agg,
                                              const ushort_t* __restrict__ WsPk,
                                              const ushort_t* __restrict__ WnPk,
                                              const float* __restrict__ bias,
                                              void* __restrict__ outp, int N) {
    __shared__ ushort_t Wl[32768];                       // Ws | Wn
    int wave = blockIdx.x * 4 + (threadIdx.x >> 6);
    int row0 = wave * 32;
    int l = threadIdx.x & 63;
    int ar0 = row0 + (l & 15); if (ar0 >= N) ar0 = N - 1;
    int ar1 = ar0 + 16;        if (ar1 >= N) ar1 = N - 1;
    int ac = (l >> 4) * 8;
    short8 ah0[4], ah1[4], ag0[4], ag1[4];
#pragma unroll
    for (int s = 0; s < 4; ++s) {
        ah0[s] = *(const short8*)&h[(size_t)ar0 * HD + s * 32 + ac];
        ah1[s] = *(const short8*)&h[(size_t)ar1 * HD + s * 32 + ac];
        ag0[s] = *(const short8*)&agg[(size_t)ar0 * HD + s * 32 + ac];
        ag1[s] = *(const short8*)&agg[(size_t)ar1 * HD + s * 32 + ac];
    }
    stage_w(WsPk, Wl, threadIdx.x);
    stage_w(WnPk, Wl + 16384, threadIdx.x);
    __syncthreads();
    if (row0 >= N) return;
    int g0 = row0 + (l & 15), g1 = g0 + 16;
    int cb0 = ((l >> 4) & 3) * 4;
#pragma unroll
    for (int t = 0; t < 8; ++t) {
        floatx4 acc0 = {0.f, 0.f, 0.f, 0.f};
        floatx4 acc1 = {0.f, 0.f, 0.f, 0.f};
#pragma unroll
        for (int s = 0; s < 4; ++s) {
            short8 ws = *(const short8*)&Wl[(t * 4 + s) * 512 + l * 8];
            acc0 = __builtin_amdgcn_mfma_f32_16x16x32_bf16(ws, ah0[s], acc0, 0, 0, 0);
            acc1 = __builtin_amdgcn_mfma_f32_16x16x32_bf16(ws, ah1[s], acc1, 0, 0, 0);
        }
#pragma unroll
        for (int s = 0; s < 4; ++s) {
            short8 wn = *(const short8*)&Wl[16384 + (t * 4 + s) * 512 + l * 8];
            acc0 = __builtin_amdgcn_mfma_f32_16x16x32_bf16(wn, ag0[s], acc0, 0, 0, 0);
            acc1 = __builtin_amdgcn_mfma_f32_16x16x32_bf16(wn, ag1[s], acc1, 0, 0, 0);
        }
        int cb = t * 16 + cb0;
        float4 bv = *(const float4*)&bias[cb];
        if (F32OUT) {
            float* out = (float*)outp;
            if (g0 < N) {
                float4 v = make_float4(acc0[0] + bv.x, acc0[1] + bv.y,
                                       acc0[2] + bv.z, acc0[3] + bv.w);
                *(float4*)&out[(size_t)g0 * HD + cb] = v;
            }
            if (g1 < N) {
                float4 v = make_float4(acc1[0] + bv.x, acc1[1] + bv.y,
                                       acc1[2] + bv.z, acc1[3] + bv.w);
                *(float4*)&out[(size_t)g1 * HD + cb] = v;
            }
        } else {
            ushort_t* out = (ushort_t*)outp;
            store_bf16(out, g0, cb, acc0, bv, false, N);
            store_bf16(out, g1, cb, acc1, bv, false, N);
        }
    }
}

// ---------------------------------------------------------------- launch -----
extern "C" void kernel_launch(void* const* d_in, const int* in_sizes, int n_in,
                              void* d_out, int out_size, void* d_ws, size_t ws_size,
                              hipStream_t stream) {
    const int*   node_ids = (const int*)d_in[0];
    const int*   src      = (const int*)d_in[1];
    const int*   dst      = (const int*)d_in[2];
    const float* emb      = (const float*)d_in[3];
    const float* Wp1      = (const float*)d_in[4];
    const float* bp1      = (const float*)d_in[5];
    const float* Ws1      = (const float*)d_in[6];
    const float* Wn1      = (const float*)d_in[7];
    const float* b1       = (const float*)d_in[8];
    const float* Wp2      = (const float*)d_in[9];
    const float* bp2      = (const float*)d_in[10];
    const float* Ws2      = (const float*)d_in[11];
    const float* Wn2      = (const float*)d_in[12];
    const float* b2       = (const float*)d_in[13];
    float* out = (float*)d_out;

    const int N = in_sizes[0];
    const int E = in_sizes[1];

    char* ws = (char*)d_ws;
    int* rp = (int*)ws;
    size_t off = (((size_t)(N + 1) * 4) + 255) & ~(size_t)255;
    ushort_t* Wpk  = (ushort_t*)(ws + off);              // 6 x 128x128 bf16
    ushort_t* h0   = Wpk + 6 * 16384;
    ushort_t* h1   = h0 + (size_t)N * HD;
    ushort_t* bufM = h1 + (size_t)N * HD;                // col-group-major [4][N][32]
    ushort_t* bufA = bufM + (size_t)N * HD;

    const int nbR = (N + 1 + 255) / 256;
    const int nbP = 6 * 64;
    const int nb_gemm = (N + 127) / 128;                 // 4 waves x 32 rows
    const int nb_seg  = ((N + 15) / 16) * 4;             // 4 col-groups x node-blocks

    k_prep<<<nbR + nbP, 256, 0, stream>>>(dst, E, rp, N,
                                          Wp1, Ws1, Wn1, Wp2, Ws2, Wn2, Wpk, nbR);

    const ushort_t* Wp1k = Wpk;
    const ushort_t* Ws1k = Wpk + 16384;
    const ushort_t* Wn1k = Wpk + 2 * 16384;
    const ushort_t* Wp2k = Wpk + 3 * 16384;
    const ushort_t* Ws2k = Wpk + 4 * 16384;
    const ushort_t* Wn2k = Wpk + 5 * 16384;

    // layer 1
    k_gather_pool<<<nb_gemm, 256, 0, stream>>>(node_ids, emb, Wp1k, bp1, h0, bufM, N);
    k_segmax<<<nb_seg, 256, 0, stream>>>(bufM, src, rp, bufA, N);
    k_dual<false><<<nb_gemm, 256, 0, stream>>>(h0, bufA, Ws1k, Wn1k, b1, h1, N);
    // layer 2
    k_pool<<<nb_gemm, 256, 0, stream>>>(h1, Wp2k, bp2, bufM, N);
    k_segmax<<<nb_seg, 256, 0, stream>>>(bufM, src, rp, bufA, N);
    k_dual<true><<<nb_gemm, 256, 0, stream>>>(h1, bufA, Ws2k, Wn2k, b2, out, N);
}

// Round 4
// 246.750 us; speedup vs baseline: 1.4854x; 1.0336x over previous
//
#include <hip/hip_runtime.h>

#define HD 128

typedef __attribute__((ext_vector_type(8))) short short8;   // 8 bf16
typedef __attribute__((ext_vector_type(4))) float floatx4;  // MFMA accumulator
typedef __attribute__((ext_vector_type(2))) unsigned short ushort2v;
typedef __attribute__((ext_vector_type(4))) unsigned int uint4v;

typedef unsigned short ushort_t;
typedef unsigned int uint_t;

// ---------------------------------------------------------------- helpers ----
__device__ __forceinline__ ushort_t f2b(float f) {          // fp32 -> bf16 RNE
    union { float f; uint_t u; } v; v.f = f;
    uint_t r = v.u + 0x7fff + ((v.u >> 16) & 1);
    return (ushort_t)(r >> 16);
}
__device__ __forceinline__ short8 cvt8(const float* __restrict__ p) {
    float4 u = *(const float4*)p, v = *(const float4*)(p + 4);
    short8 r;
    r[0] = (short)f2b(u.x); r[1] = (short)f2b(u.y); r[2] = (short)f2b(u.z); r[3] = (short)f2b(u.w);
    r[4] = (short)f2b(v.x); r[5] = (short)f2b(v.y); r[6] = (short)f2b(v.z); r[7] = (short)f2b(v.w);
    return r;
}
// packed bf16 max: valid because m = relu(..) >= 0, so IEEE order == u16 order.
__device__ __forceinline__ uint_t pkmax(uint_t a, uint_t b) {
    return __builtin_bit_cast(uint_t,
        __builtin_elementwise_max(__builtin_bit_cast(ushort2v, a),
                                  __builtin_bit_cast(ushort2v, b)));
}

// ------------------------------------------------------------------ prep -----
// [0,nbR): rowptr (rp[i] = lower_bound(dst,i)); rest: W-pack to frag order.
// Frag map (identical for A- and B-operand): lane&15 -> non-K dim, quad*8+j -> K.
__global__ __launch_bounds__(256) void k_prep(const int* __restrict__ dst, int E,
                                              int* __restrict__ rp, int N,
                                              const float* W0, const float* W1,
                                              const float* W2, const float* W3,
                                              const float* W4, const float* W5,
                                              ushort_t* __restrict__ Wpk, int nbR) {
    int b = blockIdx.x;
    if (b < nbR) {
        int i = b * 256 + threadIdx.x;
        if (i > N) return;
        int lo = 0, hi = E;
        while (lo < hi) {
            int mid = (lo + hi) >> 1;
            if (dst[mid] < i) lo = mid + 1; else hi = mid;
        }
        rp[i] = lo;
    } else {
        int bb = b - nbR;
        const float* Ws[6] = {W0, W1, W2, W3, W4, W5};
        int mat = bb >> 6;
        int o = ((bb & 63) << 8) + threadIdx.x;
        int j = o & 7, l = (o >> 3) & 63, s = (o >> 9) & 3, t = o >> 11;
        int k = s * 32 + ((l >> 4) & 3) * 8 + j;
        int n = t * 16 + (l & 15);
        Wpk[(size_t)mat * 16384 + o] = f2b(Ws[mat][k * HD + n]);
    }
}

// ---------------------------------------------------------- W -> LDS stage ---
__device__ __forceinline__ void stage_w(const ushort_t* __restrict__ g,
                                        ushort_t* l, int tid) {
#pragma unroll
    for (int i = 0; i < 8; ++i) {
        int off = i * 2048 + tid * 8;
        *(short8*)&l[off] = *(const short8*)&g[off];
    }
}

// --------------------------------------------------------------- epilogue ----
// D = mfma(Wfrag, hfrag): lane&15 = h-row, quad*4+reg = output col within tile.
__device__ __forceinline__ void store_bf16(ushort_t* __restrict__ m, int row,
                                           int colbase, const floatx4& acc,
                                           const float4& bv, bool relu, int N) {
    if (row >= N) return;
    float v0 = acc[0] + bv.x, v1 = acc[1] + bv.y, v2 = acc[2] + bv.z, v3 = acc[3] + bv.w;
    if (relu) { v0 = fmaxf(v0, 0.f); v1 = fmaxf(v1, 0.f); v2 = fmaxf(v2, 0.f); v3 = fmaxf(v3, 0.f); }
    uint2 o; o.x = (uint_t)f2b(v0) | ((uint_t)f2b(v1) << 16);
    o.y = (uint_t)f2b(v2) | ((uint_t)f2b(v3) << 16);
    *(uint2*)&m[(size_t)row * HD + colbase] = o;
}

// m is stored col-group-major: [4 groups][N rows][32 cols] bf16.  One group's
// slice = N*64 B = 3.2 MB (fits a 4 MiB XCD L2); one row-slice = exactly one
// 64 B cache line.
__device__ __forceinline__ void store_m(ushort_t* __restrict__ m, int row,
                                        int colbase, const floatx4& acc,
                                        const float4& bv, int N) {
    if (row >= N) return;
    float v0 = fmaxf(acc[0] + bv.x, 0.f), v1 = fmaxf(acc[1] + bv.y, 0.f);
    float v2 = fmaxf(acc[2] + bv.z, 0.f), v3 = fmaxf(acc[3] + bv.w, 0.f);
    uint2 o; o.x = (uint_t)f2b(v0) | ((uint_t)f2b(v1) << 16);
    o.y = (uint_t)f2b(v2) | ((uint_t)f2b(v3) << 16);
    size_t addr = (size_t)(colbase >> 5) * ((size_t)N * 32)
                + (size_t)row * 32 + (colbase & 31);
    *(uint2*)&m[addr] = o;
}

// ------------------------------------------------------ gather + pool GEMM ---
// h0 = bf16(emb[ids]);  m = relu(h0 @ Wp + b).  A loads overlap W staging.
__global__ __launch_bounds__(256) void k_gather_pool(const int* __restrict__ ids,
                                                     const float* __restrict__ emb,
                                                     const ushort_t* __restrict__ Wpk,
                                                     const float* __restrict__ bias,
                                                     ushort_t* __restrict__ h0,
                                                     ushort_t* __restrict__ m, int N) {
    __shared__ ushort_t Wl[16384];
    int wave = blockIdx.x * 4 + (threadIdx.x >> 6);
    int row0 = wave * 32;
    int l = threadIdx.x & 63;
    int ar0 = row0 + (l & 15); if (ar0 >= N) ar0 = N - 1;
    int ar1 = ar0 + 16;        if (ar1 >= N) ar1 = N - 1;
    int ac = (l >> 4) * 8;
    int id0 = ids[ar0], id1 = ids[ar1];
    short8 a0[4], a1[4];
#pragma unroll
    for (int s = 0; s < 4; ++s) {
        a0[s] = cvt8(&emb[(size_t)id0 * HD + s * 32 + ac]);
        a1[s] = cvt8(&emb[(size_t)id1 * HD + s * 32 + ac]);
    }
    stage_w(Wpk, Wl, threadIdx.x);
    __syncthreads();
    if (row0 >= N) return;
#pragma unroll
    for (int s = 0; s < 4; ++s) {
        *(short8*)&h0[(size_t)ar0 * HD + s * 32 + ac] = a0[s];
        *(short8*)&h0[(size_t)ar1 * HD + s * 32 + ac] = a1[s];
    }
    int g0 = row0 + (l & 15), g1 = g0 + 16;
    int cb0 = ((l >> 4) & 3) * 4;
#pragma unroll
    for (int t = 0; t < 8; ++t) {
        floatx4 acc0 = {0.f, 0.f, 0.f, 0.f};
        floatx4 acc1 = {0.f, 0.f, 0.f, 0.f};
#pragma unroll
        for (int s = 0; s < 4; ++s) {
            short8 w = *(const short8*)&Wl[(t * 4 + s) * 512 + l * 8];
            acc0 = __builtin_amdgcn_mfma_f32_16x16x32_bf16(w, a0[s], acc0, 0, 0, 0);
            acc1 = __builtin_amdgcn_mfma_f32_16x16x32_bf16(w, a1[s], acc1, 0, 0, 0);
        }
        int cb = t * 16 + cb0;
        float4 bv = *(const float4*)&bias[cb];
        store_m(m, g0, cb, acc0, bv, N);
        store_m(m, g1, cb, acc1, bv, N);
    }
}

// ----------------------------------------------------------- pool GEMM only --
__global__ __launch_bounds__(256) void k_pool(const ushort_t* __restrict__ h,
                                              const ushort_t* __restrict__ Wpk,
                                              const float* __restrict__ bias,
                                              ushort_t* __restrict__ m, int N) {
    __shared__ ushort_t Wl[16384];
    int wave = blockIdx.x * 4 + (threadIdx.x >> 6);
    int row0 = wave * 32;
    int l = threadIdx.x & 63;
    int ar0 = row0 + (l & 15); if (ar0 >= N) ar0 = N - 1;
    int ar1 = ar0 + 16;        if (ar1 >= N) ar1 = N - 1;
    int ac = (l >> 4) * 8;
    short8 a0[4], a1[4];
#pragma unroll
    for (int s = 0; s < 4; ++s) {
        a0[s] = *(const short8*)&h[(size_t)ar0 * HD + s * 32 + ac];
        a1[s] = *(const short8*)&h[(size_t)ar1 * HD + s * 32 + ac];
    }
    stage_w(Wpk, Wl, threadIdx.x);
    __syncthreads();
    if (row0 >= N) return;
    int g0 = row0 + (l & 15), g1 = g0 + 16;
    int cb0 = ((l >> 4) & 3) * 4;
#pragma unroll
    for (int t = 0; t < 8; ++t) {
        floatx4 acc0 = {0.f, 0.f, 0.f, 0.f};
        floatx4 acc1 = {0.f, 0.f, 0.f, 0.f};
#pragma unroll
        for (int s = 0; s < 4; ++s) {
            short8 w = *(const short8*)&Wl[(t * 4 + s) * 512 + l * 8];
            acc0 = __builtin_amdgcn_mfma_f32_16x16x32_bf16(w, a0[s], acc0, 0, 0, 0);
            acc1 = __builtin_amdgcn_mfma_f32_16x16x32_bf16(w, a1[s], acc1, 0, 0, 0);
        }
        int cb = t * 16 + cb0;
        float4 bv = *(const float4*)&bias[cb];
        store_m(m, g0, cb, acc0, bv, N);
        store_m(m, g1, cb, acc1, bv, N);
    }
}

// ---------------------------------------------------------------- segmax -----
// [4][N][32] col-group layout (L2-resident 3.2 MB slice per group).  Wave = 4
// nodes; each edge row-slice = one 64 B line gathered by a 4-lane quad.
// Phase A: predicated 2-round gather (covers deg<=32, P(deg>32)~1e-4 for
// Poisson-16) for ALL 4 nodes in one static unroll -> up to 8 independent
// uint4 gathers in flight, zero clamp-waste for deg<=16.  Phase B: fold +
// rare tail + select-trick slot reduction (16 ops vs 32).
__global__ __launch_bounds__(256) void k_segmax(const ushort_t* __restrict__ m,
                                                const int* __restrict__ src,
                                                const int* __restrict__ rp,
                                                ushort_t* __restrict__ agg, int N) {
    int cg = blockIdx.x & 3;
    int l = threadIdx.x & 63;
    int slot = l >> 2;                 // 0..15 edge slot
    int c = l & 3;                     // 16 B (4 u32) within the 64 B row-slice
    int node0 = ((blockIdx.x >> 2) * 4 + (threadIdx.x >> 6)) * 4;
    if (node0 >= N) return;
    const uint_t* __restrict__ mg = (const uint_t*)m + (size_t)cg * ((size_t)N * 16);
    uint_t* __restrict__ aggw = (uint_t*)agg;

    int bg[4], en[4], sv[4], deg[4];
#pragma unroll
    for (int nn = 0; nn < 4; ++nn) {
        int node = node0 + nn;
        bg[nn] = (node < N) ? rp[node] : 0;
        en[nn] = (node < N) ? rp[node + 1] : 0;
        deg[nn] = en[nn] - bg[nn];
    }
#pragma unroll
    for (int nn = 0; nn < 4; ++nn) {   // all 4 src loads in flight
        int si = bg[nn] + l, lim = en[nn] - 1;
        si = si > lim ? lim : si; si = si < 0 ? 0 : si;
        sv[nn] = __builtin_nontemporal_load(&src[si]);
    }

    // ---- phase A: issue gathers for edge rounds 0 and 1, all 4 nodes ----
    uint4v p0[4], p1[4];
#pragma unroll
    for (int nn = 0; nn < 4; ++nn) {
        if (deg[nn] > 0) {
            int i0 = slot; if (i0 > deg[nn] - 1) i0 = deg[nn] - 1;
            int s0 = __shfl(sv[nn], i0);
            p0[nn] = *(const uint4v*)&mg[(size_t)s0 * 16 + c * 4];
        }
        if (deg[nn] > 16) {
            int i1 = 16 + slot; if (i1 > deg[nn] - 1) i1 = deg[nn] - 1;
            int s1 = __shfl(sv[nn], i1);
            p1[nn] = *(const uint4v*)&mg[(size_t)s1 * 16 + c * 4];
        }
    }

    // ---- phase B: fold + rare tail + reduce + store ----
    int b0 = slot & 1, b1 = (slot >> 1) & 1;
#pragma unroll
    for (int nn = 0; nn < 4; ++nn) {
        int node = node0 + nn;
        if (node >= N) continue;
        uint_t a0 = 0u, a1 = 0u, a2 = 0u, a3 = 0u;
        if (deg[nn] > 0) { a0 = p0[nn].x; a1 = p0[nn].y; a2 = p0[nn].z; a3 = p0[nn].w; }
        if (deg[nn] > 16) {
            a0 = pkmax(a0, p1[nn].x); a1 = pkmax(a1, p1[nn].y);
            a2 = pkmax(a2, p1[nn].z); a3 = pkmax(a3, p1[nn].w);
        }
        if (deg[nn] > 32) {            // rare (Poisson-16 tail)
            int beg = bg[nn], end = en[nn];
            int svc = sv[nn];
            int last = (end - beg < 64 ? end - beg : 64) - 1;
            for (int o = 32; o <= last; o += 16) {
                int i = o + slot; if (i > last) i = last;
                int s = __shfl(svc, i);
                uint4v p = *(const uint4v*)&mg[(size_t)s * 16 + c * 4];
                a0 = pkmax(a0, p.x); a1 = pkmax(a1, p.y);
                a2 = pkmax(a2, p.z); a3 = pkmax(a3, p.w);
            }
            for (int base = beg + 64; base < end; base += 64) {
                int lim = end - 1;
                int si = base + l; if (si > lim) si = lim;
                svc = __builtin_nontemporal_load(&src[si]);
                int nb = end - base; if (nb > 64) nb = 64;
                int lst = nb - 1;
                for (int o = 0; o <= lst; o += 16) {
                    int i = o + slot; if (i > lst) i = lst;
                    int s = __shfl(svc, i);
                    uint4v p = *(const uint4v*)&mg[(size_t)s * 16 + c * 4];
                    a0 = pkmax(a0, p.x); a1 = pkmax(a1, p.y);
                    a2 = pkmax(a2, p.z); a3 = pkmax(a3, p.w);
                }
            }
        }
        // select-trick reduction over 16 slots (lane bits 2..5).
        // step d=4 (slot bit0): b0=0 lanes keep words {0,1}, b0=1 keep {2,3}
        uint_t q0 = b0 ? a2 : a0, q1 = b0 ? a3 : a1;
        uint_t r0 = b0 ? a0 : a2, r1 = b0 ? a1 : a3;
        q0 = pkmax(q0, (uint_t)__shfl_xor((int)r0, 4));
        q1 = pkmax(q1, (uint_t)__shfl_xor((int)r1, 4));
        // step d=8 (slot bit1): keep q0 at b1=0, q1 at b1=1
        uint_t s_ = b1 ? q1 : q0, t_ = b1 ? q0 : q1;
        s_ = pkmax(s_, (uint_t)__shfl_xor((int)t_, 8));
        // steps d=16,32 (slot bits 2,3)
        s_ = pkmax(s_, (uint_t)__shfl_xor((int)s_, 16));
        s_ = pkmax(s_, (uint_t)__shfl_xor((int)s_, 32));
        // lane now holds word c*4 + (2*b0 + b1); slots 0..3 write (one line)
        if (slot < 4)
            __builtin_nontemporal_store(s_,
                &aggw[(size_t)node * 64 + cg * 16 + c * 4 + 2 * b0 + b1]);
    }
}

// ----------------------------------------------------------- dual GEMM -------
// out = h @ Wself + agg @ Wneigh + b; A/agg loads overlap W staging.
template <bool F32OUT>
__global__ __launch_bounds__(256) void k_dual(const ushort_t* __restrict__ h,
                                              const ushort_t* __restrict__ agg,
                                              const ushort_t* __restrict__ WsPk,
                                              const ushort_t* __restrict__ WnPk,
                                              const float* __restrict__ bias,
                                              void* __restrict__ outp, int N) {
    __shared__ ushort_t Wl[32768];                       // Ws | Wn
    int wave = blockIdx.x * 4 + (threadIdx.x >> 6);
    int row0 = wave * 32;
    int l = threadIdx.x & 63;
    int ar0 = row0 + (l & 15); if (ar0 >= N) ar0 = N - 1;
    int ar1 = ar0 + 16;        if (ar1 >= N) ar1 = N - 1;
    int ac = (l >> 4) * 8;
    short8 ah0[4], ah1[4], ag0[4], ag1[4];
#pragma unroll
    for (int s = 0; s < 4; ++s) {
        ah0[s] = *(const short8*)&h[(size_t)ar0 * HD + s * 32 + ac];
        ah1[s] = *(const short8*)&h[(size_t)ar1 * HD + s * 32 + ac];
        ag0[s] = *(const short8*)&agg[(size_t)ar0 * HD + s * 32 + ac];
        ag1[s] = *(const short8*)&agg[(size_t)ar1 * HD + s * 32 + ac];
    }
    stage_w(WsPk, Wl, threadIdx.x);
    stage_w(WnPk, Wl + 16384, threadIdx.x);
    __syncthreads();
    if (row0 >= N) return;
    int g0 = row0 + (l & 15), g1 = g0 + 16;
    int cb0 = ((l >> 4) & 3) * 4;
#pragma unroll
    for (int t = 0; t < 8; ++t) {
        floatx4 acc0 = {0.f, 0.f, 0.f, 0.f};
        floatx4 acc1 = {0.f, 0.f, 0.f, 0.f};
#pragma unroll
        for (int s = 0; s < 4; ++s) {
            short8 ws = *(const short8*)&Wl[(t * 4 + s) * 512 + l * 8];
            acc0 = __builtin_amdgcn_mfma_f32_16x16x32_bf16(ws, ah0[s], acc0, 0, 0, 0);
            acc1 = __builtin_amdgcn_mfma_f32_16x16x32_bf16(ws, ah1[s], acc1, 0, 0, 0);
        }
#pragma unroll
        for (int s = 0; s < 4; ++s) {
            short8 wn = *(const short8*)&Wl[16384 + (t * 4 + s) * 512 + l * 8];
            acc0 = __builtin_amdgcn_mfma_f32_16x16x32_bf16(wn, ag0[s], acc0, 0, 0, 0);
            acc1 = __builtin_amdgcn_mfma_f32_16x16x32_bf16(wn, ag1[s], acc1, 0, 0, 0);
        }
        int cb = t * 16 + cb0;
        float4 bv = *(const float4*)&bias[cb];
        if (F32OUT) {
            float* out = (float*)outp;
            if (g0 < N) {
                float4 v = make_float4(acc0[0] + bv.x, acc0[1] + bv.y,
                                       acc0[2] + bv.z, acc0[3] + bv.w);
                *(float4*)&out[(size_t)g0 * HD + cb] = v;
            }
            if (g1 < N) {
                float4 v = make_float4(acc1[0] + bv.x, acc1[1] + bv.y,
                                       acc1[2] + bv.z, acc1[3] + bv.w);
                *(float4*)&out[(size_t)g1 * HD + cb] = v;
            }
        } else {
            ushort_t* out = (ushort_t*)outp;
            store_bf16(out, g0, cb, acc0, bv, false, N);
            store_bf16(out, g1, cb, acc1, bv, false, N);
        }
    }
}

// ---------------------------------------------------------------- launch -----
extern "C" void kernel_launch(void* const* d_in, const int* in_sizes, int n_in,
                              void* d_out, int out_size, void* d_ws, size_t ws_size,
                              hipStream_t stream) {
    const int*   node_ids = (const int*)d_in[0];
    const int*   src      = (const int*)d_in[1];
    const int*   dst      = (const int*)d_in[2];
    const float* emb      = (const float*)d_in[3];
    const float* Wp1      = (const float*)d_in[4];
    const float* bp1      = (const float*)d_in[5];
    const float* Ws1      = (const float*)d_in[6];
    const float* Wn1      = (const float*)d_in[7];
    const float* b1       = (const float*)d_in[8];
    const float* Wp2      = (const float*)d_in[9];
    const float* bp2      = (const float*)d_in[10];
    const float* Ws2      = (const float*)d_in[11];
    const float* Wn2      = (const float*)d_in[12];
    const float* b2       = (const float*)d_in[13];
    float* out = (float*)d_out;

    const int N = in_sizes[0];
    const int E = in_sizes[1];

    char* ws = (char*)d_ws;
    int* rp = (int*)ws;
    size_t off = (((size_t)(N + 1) * 4) + 255) & ~(size_t)255;
    ushort_t* Wpk  = (ushort_t*)(ws + off);              // 6 x 128x128 bf16
    ushort_t* h0   = Wpk + 6 * 16384;
    ushort_t* h1   = h0 + (size_t)N * HD;
    ushort_t* bufM = h1 + (size_t)N * HD;                // col-group-major [4][N][32]
    ushort_t* bufA = bufM + (size_t)N * HD;

    const int nbR = (N + 1 + 255) / 256;
    const int nbP = 6 * 64;
    const int nb_gemm = (N + 127) / 128;                 // 4 waves x 32 rows
    const int nb_seg  = ((N + 15) / 16) * 4;             // 4 col-groups x node-blocks

    k_prep<<<nbR + nbP, 256, 0, stream>>>(dst, E, rp, N,
                                          Wp1, Ws1, Wn1, Wp2, Ws2, Wn2, Wpk, nbR);

    const ushort_t* Wp1k = Wpk;
    const ushort_t* Ws1k = Wpk + 16384;
    const ushort_t* Wn1k = Wpk + 2 * 16384;
    const ushort_t* Wp2k = Wpk + 3 * 16384;
    const ushort_t* Ws2k = Wpk + 4 * 16384;
    const ushort_t* Wn2k = Wpk + 5 * 16384;

    // layer 1
    k_gather_pool<<<nb_gemm, 256, 0, stream>>>(node_ids, emb, Wp1k, bp1, h0, bufM, N);
    k_segmax<<<nb_seg, 256, 0, stream>>>(bufM, src, rp, bufA, N);
    k_dual<false><<<nb_gemm, 256, 0, stream>>>(h0, bufA, Ws1k, Wn1k, b1, h1, N);
    // layer 2
    k_pool<<<nb_gemm, 256, 0, stream>>>(h1, Wp2k, bp2, bufM, N);
    k_segmax<<<nb_seg, 256, 0, stream>>>(bufM, src, rp, bufA, N);
    k_dual<true><<<nb_gemm, 256, 0, stream>>>(h1, bufA, Ws2k, Wn2k, b2, out, N);
}

// Round 5
// 246.448 us; speedup vs baseline: 1.4872x; 1.0012x over previous
//
#include <hip/hip_runtime.h>

#define HD 128

typedef __attribute__((ext_vector_type(8))) short short8;   // 8 bf16
typedef __attribute__((ext_vector_type(4))) float floatx4;  // MFMA accumulator
typedef __attribute__((ext_vector_type(2))) unsigned short ushort2v;
typedef __attribute__((ext_vector_type(4))) unsigned int uint4v;

typedef unsigned short ushort_t;
typedef unsigned int uint_t;

// ---------------------------------------------------------------- helpers ----
__device__ __forceinline__ ushort_t f2b(float f) {          // fp32 -> bf16 RNE
    union { float f; uint_t u; } v; v.f = f;
    uint_t r = v.u + 0x7fff + ((v.u >> 16) & 1);
    return (ushort_t)(r >> 16);
}
__device__ __forceinline__ short8 cvt8(const float* __restrict__ p) {
    float4 u = *(const float4*)p, v = *(const float4*)(p + 4);
    short8 r;
    r[0] = (short)f2b(u.x); r[1] = (short)f2b(u.y); r[2] = (short)f2b(u.z); r[3] = (short)f2b(u.w);
    r[4] = (short)f2b(v.x); r[5] = (short)f2b(v.y); r[6] = (short)f2b(v.z); r[7] = (short)f2b(v.w);
    return r;
}
// packed bf16 max: valid because m = relu(..) >= 0, so IEEE order == u16 order.
__device__ __forceinline__ uint_t pkmax(uint_t a, uint_t b) {
    return __builtin_bit_cast(uint_t,
        __builtin_elementwise_max(__builtin_bit_cast(ushort2v, a),
                                  __builtin_bit_cast(ushort2v, b)));
}
__device__ __forceinline__ int lbound(const int* __restrict__ dst, int E, int v) {
    int lo = 0, hi = E;
    while (lo < hi) {
        int mid = (lo + hi) >> 1;
        if (dst[mid] < v) lo = mid + 1; else hi = mid;
    }
    return lo;
}

// ------------------------------------------------------------------ prep -----
// [0,nbR): rowptr.  [nbR,nbR+nbP): W-pack to frag order.  rest: srcPad build —
// per node a 32-slot clamp-padded edge list (slot j = src[beg+min(j,deg-1)]),
// so segmax needs no shfl/clamp logic.  srcPad blocks do their own binary
// searches (no dependence on rp ordering within this launch).
__global__ __launch_bounds__(256) void k_prep(const int* __restrict__ dst, int E,
                                              const int* __restrict__ src,
                                              int* __restrict__ rp, int N,
                                              int* __restrict__ srcPad,
                                              const float* W0, const float* W1,
                                              const float* W2, const float* W3,
                                              const float* W4, const float* W5,
                                              ushort_t* __restrict__ Wpk,
                                              int nbR, int nbP) {
    int b = blockIdx.x;
    if (b < nbR) {
        int i = b * 256 + threadIdx.x;
        if (i > N) return;
        rp[i] = lbound(dst, E, i);
    } else if (b < nbR + nbP) {
        int bb = b - nbR;
        const float* Ws[6] = {W0, W1, W2, W3, W4, W5};
        int mat = bb >> 6;
        int o = ((bb & 63) << 8) + threadIdx.x;
        int j = o & 7, l = (o >> 3) & 63, s = (o >> 9) & 3, t = o >> 11;
        int k = s * 32 + ((l >> 4) & 3) * 8 + j;
        int n = t * 16 + (l & 15);
        Wpk[(size_t)mat * 16384 + o] = f2b(Ws[mat][k * HD + n]);
    } else {
        // srcPad: idx = node*32 + j.  Lanes 0-15 of each 32-lane group search
        // `node`, lanes 16-31 search `node+1`; exchange via shfl.
        int idx = (b - nbR - nbP) * 256 + threadIdx.x;
        int node = idx >> 5;
        if (node >= N) return;
        int j = idx & 31;
        int lane = threadIdx.x & 63;
        int half = (lane & 31) >> 4;
        int lo = lbound(dst, E, node + half);
        int base = lane & 32;
        int beg = __shfl(lo, base);
        int end = __shfl(lo, base + 16);
        int deg = end - beg;
        int val = 0;
        if (deg > 0) val = src[beg + (j < deg ? j : deg - 1)];
        srcPad[(size_t)node * 32 + j] = val;
    }
}

// ---------------------------------------------------------- W -> LDS stage ---
__device__ __forceinline__ void stage_w(const ushort_t* __restrict__ g,
                                        ushort_t* l, int tid) {
#pragma unroll
    for (int i = 0; i < 8; ++i) {
        int off = i * 2048 + tid * 8;
        *(short8*)&l[off] = *(const short8*)&g[off];
    }
}
__device__ __forceinline__ void stage_w_half(const ushort_t* __restrict__ g,
                                             ushort_t* l, int tid) {
#pragma unroll
    for (int i = 0; i < 4; ++i) {
        int off = i * 2048 + tid * 8;
        *(short8*)&l[off] = *(const short8*)&g[off];
    }
}

// --------------------------------------------------------------- epilogue ----
// D = mfma(Wfrag, hfrag): lane&15 = h-row, quad*4+reg = output col within tile.
__device__ __forceinline__ void store_bf16(ushort_t* __restrict__ m, int row,
                                           int colbase, const floatx4& acc,
                                           const float4& bv, bool relu, int N) {
    if (row >= N) return;
    float v0 = acc[0] + bv.x, v1 = acc[1] + bv.y, v2 = acc[2] + bv.z, v3 = acc[3] + bv.w;
    if (relu) { v0 = fmaxf(v0, 0.f); v1 = fmaxf(v1, 0.f); v2 = fmaxf(v2, 0.f); v3 = fmaxf(v3, 0.f); }
    uint2 o; o.x = (uint_t)f2b(v0) | ((uint_t)f2b(v1) << 16);
    o.y = (uint_t)f2b(v2) | ((uint_t)f2b(v3) << 16);
    *(uint2*)&m[(size_t)row * HD + colbase] = o;
}

// m is stored col-group-major: [4 groups][N rows][32 cols] bf16.  One group's
// slice = N*64 B = 3.2 MB (fits a 4 MiB XCD L2); one row-slice = one 64 B line.
__device__ __forceinline__ void store_m(ushort_t* __restrict__ m, int row,
                                        int colbase, const floatx4& acc,
                                        const float4& bv, int N) {
    if (row >= N) return;
    float v0 = fmaxf(acc[0] + bv.x, 0.f), v1 = fmaxf(acc[1] + bv.y, 0.f);
    float v2 = fmaxf(acc[2] + bv.z, 0.f), v3 = fmaxf(acc[3] + bv.w, 0.f);
    uint2 o; o.x = (uint_t)f2b(v0) | ((uint_t)f2b(v1) << 16);
    o.y = (uint_t)f2b(v2) | ((uint_t)f2b(v3) << 16);
    size_t addr = (size_t)(colbase >> 5) * ((size_t)N * 32)
                + (size_t)row * 32 + (colbase & 31);
    *(uint2*)&m[addr] = o;
}

// ------------------------------------------------------ gather + pool GEMM ---
// h0 = bf16(emb[ids]);  m = relu(h0 @ Wp + b).  A loads overlap W staging.
// Unsplit (emb HBM gather must happen exactly once).
__global__ __launch_bounds__(256) void k_gather_pool(const int* __restrict__ ids,
                                                     const float* __restrict__ emb,
                                                     const ushort_t* __restrict__ Wpk,
                                                     const float* __restrict__ bias,
                                                     ushort_t* __restrict__ h0,
                                                     ushort_t* __restrict__ m, int N) {
    __shared__ ushort_t Wl[16384];
    int wave = blockIdx.x * 4 + (threadIdx.x >> 6);
    int row0 = wave * 32;
    int l = threadIdx.x & 63;
    int ar0 = row0 + (l & 15); if (ar0 >= N) ar0 = N - 1;
    int ar1 = ar0 + 16;        if (ar1 >= N) ar1 = N - 1;
    int ac = (l >> 4) * 8;
    int id0 = ids[ar0], id1 = ids[ar1];
    short8 a0[4], a1[4];
#pragma unroll
    for (int s = 0; s < 4; ++s) {
        a0[s] = cvt8(&emb[(size_t)id0 * HD + s * 32 + ac]);
        a1[s] = cvt8(&emb[(size_t)id1 * HD + s * 32 + ac]);
    }
    stage_w(Wpk, Wl, threadIdx.x);
    __syncthreads();
    if (row0 >= N) return;
#pragma unroll
    for (int s = 0; s < 4; ++s) {
        *(short8*)&h0[(size_t)ar0 * HD + s * 32 + ac] = a0[s];
        *(short8*)&h0[(size_t)ar1 * HD + s * 32 + ac] = a1[s];
    }
    int g0 = row0 + (l & 15), g1 = g0 + 16;
    int cb0 = ((l >> 4) & 3) * 4;
#pragma unroll
    for (int t = 0; t < 8; ++t) {
        floatx4 acc0 = {0.f, 0.f, 0.f, 0.f};
        floatx4 acc1 = {0.f, 0.f, 0.f, 0.f};
#pragma unroll
        for (int s = 0; s < 4; ++s) {
            short8 w = *(const short8*)&Wl[(t * 4 + s) * 512 + l * 8];
            acc0 = __builtin_amdgcn_mfma_f32_16x16x32_bf16(w, a0[s], acc0, 0, 0, 0);
            acc1 = __builtin_amdgcn_mfma_f32_16x16x32_bf16(w, a1[s], acc1, 0, 0, 0);
        }
        int cb = t * 16 + cb0;
        float4 bv = *(const float4*)&bias[cb];
        store_m(m, g0, cb, acc0, bv, N);
        store_m(m, g1, cb, acc1, bv, N);
    }
}

// ----------------------------------------------------------- pool GEMM only --
// Col-split: bid&1 selects 64 output cols (t-tiles 0-3 or 4-7).  Halves the
// per-block serial W-stage and doubles block count (tail/occupancy).
__global__ __launch_bounds__(256) void k_pool(const ushort_t* __restrict__ h,
                                              const ushort_t* __restrict__ Wpk,
                                              const float* __restrict__ bias,
                                              ushort_t* __restrict__ m, int N) {
    __shared__ ushort_t Wl[8192];
    int colhalf = blockIdx.x & 1;
    int wave = (blockIdx.x >> 1) * 4 + (threadIdx.x >> 6);
    int row0 = wave * 32;
    int l = threadIdx.x & 63;
    int ar0 = row0 + (l & 15); if (ar0 >= N) ar0 = N - 1;
    int ar1 = ar0 + 16;        if (ar1 >= N) ar1 = N - 1;
    int ac = (l >> 4) * 8;
    short8 a0[4], a1[4];
#pragma unroll
    for (int s = 0; s < 4; ++s) {
        a0[s] = *(const short8*)&h[(size_t)ar0 * HD + s * 32 + ac];
        a1[s] = *(const short8*)&h[(size_t)ar1 * HD + s * 32 + ac];
    }
    stage_w_half(Wpk + colhalf * 8192, Wl, threadIdx.x);
    __syncthreads();
    if (row0 >= N) return;
    int g0 = row0 + (l & 15), g1 = g0 + 16;
    int cb0 = ((l >> 4) & 3) * 4;
#pragma unroll
    for (int t = 0; t < 4; ++t) {
        floatx4 acc0 = {0.f, 0.f, 0.f, 0.f};
        floatx4 acc1 = {0.f, 0.f, 0.f, 0.f};
#pragma unroll
        for (int s = 0; s < 4; ++s) {
            short8 w = *(const short8*)&Wl[(t * 4 + s) * 512 + l * 8];
            acc0 = __builtin_amdgcn_mfma_f32_16x16x32_bf16(w, a0[s], acc0, 0, 0, 0);
            acc1 = __builtin_amdgcn_mfma_f32_16x16x32_bf16(w, a1[s], acc1, 0, 0, 0);
        }
        int cb = (colhalf * 4 + t) * 16 + cb0;
        float4 bv = *(const float4*)&bias[cb];
        store_m(m, g0, cb, acc0, bv, N);
        store_m(m, g1, cb, acc1, bv, N);
    }
}

// ---------------------------------------------------------------- segmax -----
// [4][N][32] col-group layout (L2-resident 3.2 MB slice per group).  Wave = 4
// nodes, 16 slots x 4-lane quads (16 B/lane, one 64 B line per edge).
// srcPad gives a clamp-padded 32-slot edge list: no shfl, no clamp math, all
// 8 srcPad loads + 8 gathers independent (deep MLP).  Round-1 fold is
// unconditional (clamp dups idempotent under max).  deg>32 tail is rare
// (Poisson-16, P ~ 1e-4).
__global__ __launch_bounds__(256) void k_segmax(const ushort_t* __restrict__ m,
                                                const int* __restrict__ srcPad,
                                                const int* __restrict__ src,
                                                const int* __restrict__ rp,
                                                ushort_t* __restrict__ agg, int N) {
    int cg = blockIdx.x & 3;
    int l = threadIdx.x & 63;
    int slot = l >> 2;                 // 0..15 edge slot
    int c = l & 3;                     // 16 B (4 u32) within the 64 B row-slice
    int node0 = ((blockIdx.x >> 2) * 4 + (threadIdx.x >> 6)) * 4;
    if (node0 >= N) return;
    const uint_t* __restrict__ mg = (const uint_t*)m + (size_t)cg * ((size_t)N * 16);
    uint_t* __restrict__ aggw = (uint_t*)agg;

    int nd[4], s0[4], s1[4], deg[4];
#pragma unroll
    for (int nn = 0; nn < 4; ++nn) {
        int node = node0 + nn; if (node >= N) node = N - 1;
        nd[nn] = node;
    }
#pragma unroll
    for (int nn = 0; nn < 4; ++nn) {   // 8 coalesced srcPad loads in flight
        s0[nn] = srcPad[(size_t)nd[nn] * 32 + slot];
        s1[nn] = srcPad[(size_t)nd[nn] * 32 + 16 + slot];
    }
#pragma unroll
    for (int nn = 0; nn < 4; ++nn)
        deg[nn] = rp[nd[nn] + 1] - rp[nd[nn]];
    uint4v p0[4], p1[4];
#pragma unroll
    for (int nn = 0; nn < 4; ++nn) {   // 8 independent gathers in flight
        p0[nn] = *(const uint4v*)&mg[(size_t)s0[nn] * 16 + c * 4];
        p1[nn] = *(const uint4v*)&mg[(size_t)s1[nn] * 16 + c * 4];
    }
    int b0 = slot & 1, b1 = (slot >> 1) & 1;
#pragma unroll
    for (int nn = 0; nn < 4; ++nn) {
        int node = node0 + nn;
        if (node >= N) continue;
        uint_t a0 = 0u, a1 = 0u, a2 = 0u, a3 = 0u;
        if (deg[nn] > 0) {
            a0 = pkmax(p0[nn].x, p1[nn].x);
            a1 = pkmax(p0[nn].y, p1[nn].y);
            a2 = pkmax(p0[nn].z, p1[nn].z);
            a3 = pkmax(p0[nn].w, p1[nn].w);
        }
        if (deg[nn] > 32) {            // rare tail
            int beg = rp[node];
            int dm1 = deg[nn] - 1;
            for (int o = 32; o < deg[nn]; o += 16) {
                int i = o + slot; if (i > dm1) i = dm1;
                int s = src[beg + i];
                uint4v p = *(const uint4v*)&mg[(size_t)s * 16 + c * 4];
                a0 = pkmax(a0, p.x); a1 = pkmax(a1, p.y);
                a2 = pkmax(a2, p.z); a3 = pkmax(a3, p.w);
            }
        }
        // select-trick reduction over 16 slots (lane bits 2..5).
        uint_t q0 = b0 ? a2 : a0, q1 = b0 ? a3 : a1;
        uint_t r0 = b0 ? a0 : a2, r1 = b0 ? a1 : a3;
        q0 = pkmax(q0, (uint_t)__shfl_xor((int)r0, 4));
        q1 = pkmax(q1, (uint_t)__shfl_xor((int)r1, 4));
        uint_t s_ = b1 ? q1 : q0, t_ = b1 ? q0 : q1;
        s_ = pkmax(s_, (uint_t)__shfl_xor((int)t_, 8));
        s_ = pkmax(s_, (uint_t)__shfl_xor((int)s_, 16));
        s_ = pkmax(s_, (uint_t)__shfl_xor((int)s_, 32));
        if (slot < 4)                  // lane holds word c*4 + 2*b0 + b1
            __builtin_nontemporal_store(s_,
                &aggw[(size_t)node * 64 + cg * 16 + c * 4 + 2 * b0 + b1]);
    }
}

// ----------------------------------------------------------- dual GEMM -------
// out = h @ Wself + agg @ Wneigh + b; col-split like k_pool (32 KB LDS).
template <bool F32OUT>
__global__ __launch_bounds__(256) void k_dual(const ushort_t* __restrict__ h,
                                              const ushort_t* __restrict__ agg,
                                              const ushort_t* __restrict__ WsPk,
                                              const ushort_t* __restrict__ WnPk,
                                              const float* __restrict__ bias,
                                              void* __restrict__ outp, int N) {
    __shared__ ushort_t Wl[16384];                       // Ws-half | Wn-half
    int colhalf = blockIdx.x & 1;
    int wave = (blockIdx.x >> 1) * 4 + (threadIdx.x >> 6);
    int row0 = wave * 32;
    int l = threadIdx.x & 63;
    int ar0 = row0 + (l & 15); if (ar0 >= N) ar0 = N - 1;
    int ar1 = ar0 + 16;        if (ar1 >= N) ar1 = N - 1;
    int ac = (l >> 4) * 8;
    short8 ah0[4], ah1[4], ag0[4], ag1[4];
#pragma unroll
    for (int s = 0; s < 4; ++s) {
        ah0[s] = *(const short8*)&h[(size_t)ar0 * HD + s * 32 + ac];
        ah1[s] = *(const short8*)&h[(size_t)ar1 * HD + s * 32 + ac];
        ag0[s] = *(const short8*)&agg[(size_t)ar0 * HD + s * 32 + ac];
        ag1[s] = *(const short8*)&agg[(size_t)ar1 * HD + s * 32 + ac];
    }
    stage_w_half(WsPk + colhalf * 8192, Wl, threadIdx.x);
    stage_w_half(WnPk + colhalf * 8192, Wl + 8192, threadIdx.x);
    __syncthreads();
    if (row0 >= N) return;
    int g0 = row0 + (l & 15), g1 = g0 + 16;
    int cb0 = ((l >> 4) & 3) * 4;
#pragma unroll
    for (int t = 0; t < 4; ++t) {
        floatx4 acc0 = {0.f, 0.f, 0.f, 0.f};
        floatx4 acc1 = {0.f, 0.f, 0.f, 0.f};
#pragma unroll
        for (int s = 0; s < 4; ++s) {
            short8 ws = *(const short8*)&Wl[(t * 4 + s) * 512 + l * 8];
            acc0 = __builtin_amdgcn_mfma_f32_16x16x32_bf16(ws, ah0[s], acc0, 0, 0, 0);
            acc1 = __builtin_amdgcn_mfma_f32_16x16x32_bf16(ws, ah1[s], acc1, 0, 0, 0);
        }
#pragma unroll
        for (int s = 0; s < 4; ++s) {
            short8 wn = *(const short8*)&Wl[8192 + (t * 4 + s) * 512 + l * 8];
            acc0 = __builtin_amdgcn_mfma_f32_16x16x32_bf16(wn, ag0[s], acc0, 0, 0, 0);
            acc1 = __builtin_amdgcn_mfma_f32_16x16x32_bf16(wn, ag1[s], acc1, 0, 0, 0);
        }
        int cb = (colhalf * 4 + t) * 16 + cb0;
        float4 bv = *(const float4*)&bias[cb];
        if (F32OUT) {
            float* out = (float*)outp;
            if (g0 < N) {
                float4 v = make_float4(acc0[0] + bv.x, acc0[1] + bv.y,
                                       acc0[2] + bv.z, acc0[3] + bv.w);
                *(float4*)&out[(size_t)g0 * HD + cb] = v;
            }
            if (g1 < N) {
                float4 v = make_float4(acc1[0] + bv.x, acc1[1] + bv.y,
                                       acc1[2] + bv.z, acc1[3] + bv.w);
                *(float4*)&out[(size_t)g1 * HD + cb] = v;
            }
        } else {
            ushort_t* out = (ushort_t*)outp;
            store_bf16(out, g0, cb, acc0, bv, false, N);
            store_bf16(out, g1, cb, acc1, bv, false, N);
        }
    }
}

// ---------------------------------------------------------------- launch -----
extern "C" void kernel_launch(void* const* d_in, const int* in_sizes, int n_in,
                              void* d_out, int out_size, void* d_ws, size_t ws_size,
                              hipStream_t stream) {
    const int*   node_ids = (const int*)d_in[0];
    const int*   src      = (const int*)d_in[1];
    const int*   dst      = (const int*)d_in[2];
    const float* emb      = (const float*)d_in[3];
    const float* Wp1      = (const float*)d_in[4];
    const float* bp1      = (const float*)d_in[5];
    const float* Ws1      = (const float*)d_in[6];
    const float* Wn1      = (const float*)d_in[7];
    const float* b1       = (const float*)d_in[8];
    const float* Wp2      = (const float*)d_in[9];
    const float* bp2      = (const float*)d_in[10];
    const float* Ws2      = (const float*)d_in[11];
    const float* Wn2      = (const float*)d_in[12];
    const float* b2       = (const float*)d_in[13];
    float* out = (float*)d_out;

    const int N = in_sizes[0];
    const int E = in_sizes[1];

    char* ws = (char*)d_ws;
    int* rp = (int*)ws;
    size_t off = (((size_t)(N + 1) * 4) + 255) & ~(size_t)255;
    int* srcPad = (int*)(ws + off);                      // N x 32 padded lists
    off += (((size_t)N * 32 * 4) + 255) & ~(size_t)255;
    ushort_t* Wpk  = (ushort_t*)(ws + off);              // 6 x 128x128 bf16
    ushort_t* h0   = Wpk + 6 * 16384;
    ushort_t* h1   = h0 + (size_t)N * HD;
    ushort_t* bufM = h1 + (size_t)N * HD;                // col-group-major [4][N][32]
    ushort_t* bufA = bufM + (size_t)N * HD;

    const int nbR = (N + 1 + 255) / 256;
    const int nbP = 6 * 64;
    const int nbS = ((N * 32) + 255) / 256;              // srcPad build
    const int nb_gemm = (N + 127) / 128;                 // 4 waves x 32 rows
    const int nb_half = nb_gemm * 2;                     // col-split GEMMs
    const int nb_seg  = ((N + 15) / 16) * 4;             // 4 col-groups

    k_prep<<<nbR + nbP + nbS, 256, 0, stream>>>(dst, E, src, rp, N, srcPad,
                                                Wp1, Ws1, Wn1, Wp2, Ws2, Wn2,
                                                Wpk, nbR, nbP);

    const ushort_t* Wp1k = Wpk;
    const ushort_t* Ws1k = Wpk + 16384;
    const ushort_t* Wn1k = Wpk + 2 * 16384;
    const ushort_t* Wp2k = Wpk + 3 * 16384;
    const ushort_t* Ws2k = Wpk + 4 * 16384;
    const ushort_t* Wn2k = Wpk + 5 * 16384;

    // layer 1
    k_gather_pool<<<nb_gemm, 256, 0, stream>>>(node_ids, emb, Wp1k, bp1, h0, bufM, N);
    k_segmax<<<nb_seg, 256, 0, stream>>>(bufM, srcPad, src, rp, bufA, N);
    k_dual<false><<<nb_half, 256, 0, stream>>>(h0, bufA, Ws1k, Wn1k, b1, h1, N);
    // layer 2
    k_pool<<<nb_half, 256, 0, stream>>>(h1, Wp2k, bp2, bufM, N);
    k_segmax<<<nb_seg, 256, 0, stream>>>(bufM, srcPad, src, rp, bufA, N);
    k_dual<true><<<nb_half, 256, 0, stream>>>(h1, bufA, Ws2k, Wn2k, b2, out, N);
}

// Round 6
// 228.336 us; speedup vs baseline: 1.6052x; 1.0793x over previous
//
#include <hip/hip_runtime.h>

#define HD 128

typedef __attribute__((ext_vector_type(8))) short short8;   // 8 bf16
typedef __attribute__((ext_vector_type(4))) float floatx4;  // MFMA accumulator
typedef __attribute__((ext_vector_type(2))) unsigned short ushort2v;
typedef __attribute__((ext_vector_type(4))) unsigned int uint4v;

typedef unsigned short ushort_t;
typedef unsigned int uint_t;

// ---------------------------------------------------------------- helpers ----
__device__ __forceinline__ ushort_t f2b(float f) {          // fp32 -> bf16 RNE
    union { float f; uint_t u; } v; v.f = f;
    uint_t r = v.u + 0x7fff + ((v.u >> 16) & 1);
    return (ushort_t)(r >> 16);
}
__device__ __forceinline__ short8 cvt8(const float* __restrict__ p) {
    float4 u = *(const float4*)p, v = *(const float4*)(p + 4);
    short8 r;
    r[0] = (short)f2b(u.x); r[1] = (short)f2b(u.y); r[2] = (short)f2b(u.z); r[3] = (short)f2b(u.w);
    r[4] = (short)f2b(v.x); r[5] = (short)f2b(v.y); r[6] = (short)f2b(v.z); r[7] = (short)f2b(v.w);
    return r;
}
// packed bf16 max: valid because m = relu(..) >= 0, so IEEE order == u16 order.
__device__ __forceinline__ uint_t pkmax(uint_t a, uint_t b) {
    return __builtin_bit_cast(uint_t,
        __builtin_elementwise_max(__builtin_bit_cast(ushort2v, a),
                                  __builtin_bit_cast(ushort2v, b)));
}
__device__ __forceinline__ int lbound(const int* __restrict__ dst, int E, int v) {
    int lo = 0, hi = E;
    while (lo < hi) {
        int mid = (lo + hi) >> 1;
        if (dst[mid] < v) lo = mid + 1; else hi = mid;
    }
    return lo;
}

// ------------------------------------------------------------------ prep -----
// [0,nbR): rowptr.  [nbR,nbR+nbP): W-pack.  [nbR+nbP,...): srcPad init to the
// sentinel row N (zero row), plus one block zeroes bufM's pad row.  srcPad is
// then filled by a cheap scatter inside k_gather_pool (needs rp).
__global__ __launch_bounds__(256) void k_prep(const int* __restrict__ dst, int E,
                                              int* __restrict__ rp, int N,
                                              int* __restrict__ srcPad,
                                              ushort_t* __restrict__ bufM,
                                              const float* W0, const float* W1,
                                              const float* W2, const float* W3,
                                              const float* W4, const float* W5,
                                              ushort_t* __restrict__ Wpk,
                                              int nbR, int nbP) {
    int b = blockIdx.x;
    if (b < nbR) {
        int i = b * 256 + threadIdx.x;
        if (i > N) return;
        rp[i] = lbound(dst, E, i);
    } else if (b < nbR + nbP) {
        int bb = b - nbR;
        const float* Ws[6] = {W0, W1, W2, W3, W4, W5};
        int mat = bb >> 6;
        int o = ((bb & 63) << 8) + threadIdx.x;
        int j = o & 7, l = (o >> 3) & 63, s = (o >> 9) & 3, t = o >> 11;
        int k = s * 32 + ((l >> 4) & 3) * 8 + j;
        int n = t * 16 + (l & 15);
        Wpk[(size_t)mat * 16384 + o] = f2b(Ws[mat][k * HD + n]);
    } else {
        int bb = b - nbR - nbP;
        if (bb == 0 && threadIdx.x < 64) {   // zero bufM pad row (row N, 4 groups)
            uint_t* mz = (uint_t*)bufM;
            mz[(size_t)(threadIdx.x >> 4) * ((size_t)(N + 1) * 16)
               + (size_t)N * 16 + (threadIdx.x & 15)] = 0u;
        }
        int idx = bb * 256 + threadIdx.x;
        if (idx < N * 32) srcPad[idx] = N;   // sentinel: points at zero row
    }
}

// ---------------------------------------------------------- W -> LDS stage ---
__device__ __forceinline__ void stage_w(const ushort_t* __restrict__ g,
                                        ushort_t* l, int tid) {
#pragma unroll
    for (int i = 0; i < 8; ++i) {
        int off = i * 2048 + tid * 8;
        *(short8*)&l[off] = *(const short8*)&g[off];
    }
}
__device__ __forceinline__ void stage_w_half(const ushort_t* __restrict__ g,
                                             ushort_t* l, int tid) {
#pragma unroll
    for (int i = 0; i < 4; ++i) {
        int off = i * 2048 + tid * 8;
        *(short8*)&l[off] = *(const short8*)&g[off];
    }
}

// --------------------------------------------------------------- epilogue ----
// D = mfma(Wfrag, hfrag): lane&15 = h-row, quad*4+reg = output col within tile.
__device__ __forceinline__ void store_bf16(ushort_t* __restrict__ m, int row,
                                           int colbase, const floatx4& acc,
                                           const float4& bv, bool relu, int N) {
    if (row >= N) return;
    float v0 = acc[0] + bv.x, v1 = acc[1] + bv.y, v2 = acc[2] + bv.z, v3 = acc[3] + bv.w;
    if (relu) { v0 = fmaxf(v0, 0.f); v1 = fmaxf(v1, 0.f); v2 = fmaxf(v2, 0.f); v3 = fmaxf(v3, 0.f); }
    uint2 o; o.x = (uint_t)f2b(v0) | ((uint_t)f2b(v1) << 16);
    o.y = (uint_t)f2b(v2) | ((uint_t)f2b(v3) << 16);
    *(uint2*)&m[(size_t)row * HD + colbase] = o;
}

// m is col-group-major [4 groups][N+1 rows][32 cols] bf16; row N is the zero
// pad row.  One group slice ~3.2 MB (fits a 4 MiB XCD L2); one row-slice =
// exactly one 64 B line.
__device__ __forceinline__ void store_m(ushort_t* __restrict__ m, int row,
                                        int colbase, const floatx4& acc,
                                        const float4& bv, int N) {
    if (row >= N) return;
    float v0 = fmaxf(acc[0] + bv.x, 0.f), v1 = fmaxf(acc[1] + bv.y, 0.f);
    float v2 = fmaxf(acc[2] + bv.z, 0.f), v3 = fmaxf(acc[3] + bv.w, 0.f);
    uint2 o; o.x = (uint_t)f2b(v0) | ((uint_t)f2b(v1) << 16);
    o.y = (uint_t)f2b(v2) | ((uint_t)f2b(v3) << 16);
    size_t addr = (size_t)(colbase >> 5) * ((size_t)(N + 1) * 32)
                + (size_t)row * 32 + (colbase & 31);
    *(uint2*)&m[addr] = o;
}

// ------------------------------------------------------ gather + pool GEMM ---
// Blocks [0,nb_gemm): h0 = bf16(emb[ids]); m = relu(h0 @ Wp + b).
// Blocks [nb_gemm,..): srcPad scatter — slot j = e - rp[dst[e]], j<32.
__global__ __launch_bounds__(256) void k_gather_pool(const int* __restrict__ ids,
                                                     const float* __restrict__ emb,
                                                     const ushort_t* __restrict__ Wpk,
                                                     const float* __restrict__ bias,
                                                     ushort_t* __restrict__ h0,
                                                     ushort_t* __restrict__ m, int N,
                                                     const int* __restrict__ src,
                                                     const int* __restrict__ dst,
                                                     const int* __restrict__ rp,
                                                     int* __restrict__ srcPad,
                                                     int E, int nb_gemm) {
    if ((int)blockIdx.x >= nb_gemm) {        // ---- scatter region ----
        int e = (blockIdx.x - nb_gemm) * 256 + threadIdx.x;
        if (e < E) {
            int node = dst[e];
            int j = e - rp[node];
            if (j < 32) srcPad[(size_t)node * 32 + j] = src[e];
        }
        return;
    }
    __shared__ ushort_t Wl[16384];
    int wave = blockIdx.x * 4 + (threadIdx.x >> 6);
    int row0 = wave * 32;
    int l = threadIdx.x & 63;
    int ar0 = row0 + (l & 15); if (ar0 >= N) ar0 = N - 1;
    int ar1 = ar0 + 16;        if (ar1 >= N) ar1 = N - 1;
    int ac = (l >> 4) * 8;
    int id0 = ids[ar0], id1 = ids[ar1];
    short8 a0[4], a1[4];
#pragma unroll
    for (int s = 0; s < 4; ++s) {
        a0[s] = cvt8(&emb[(size_t)id0 * HD + s * 32 + ac]);
        a1[s] = cvt8(&emb[(size_t)id1 * HD + s * 32 + ac]);
    }
    stage_w(Wpk, Wl, threadIdx.x);
    __syncthreads();
    if (row0 >= N) return;
#pragma unroll
    for (int s = 0; s < 4; ++s) {
        *(short8*)&h0[(size_t)ar0 * HD + s * 32 + ac] = a0[s];
        *(short8*)&h0[(size_t)ar1 * HD + s * 32 + ac] = a1[s];
    }
    int g0 = row0 + (l & 15), g1 = g0 + 16;
    int cb0 = ((l >> 4) & 3) * 4;
#pragma unroll
    for (int t = 0; t < 8; ++t) {
        floatx4 acc0 = {0.f, 0.f, 0.f, 0.f};
        floatx4 acc1 = {0.f, 0.f, 0.f, 0.f};
#pragma unroll
        for (int s = 0; s < 4; ++s) {
            short8 w = *(const short8*)&Wl[(t * 4 + s) * 512 + l * 8];
            acc0 = __builtin_amdgcn_mfma_f32_16x16x32_bf16(w, a0[s], acc0, 0, 0, 0);
            acc1 = __builtin_amdgcn_mfma_f32_16x16x32_bf16(w, a1[s], acc1, 0, 0, 0);
        }
        int cb = t * 16 + cb0;
        float4 bv = *(const float4*)&bias[cb];
        store_m(m, g0, cb, acc0, bv, N);
        store_m(m, g1, cb, acc1, bv, N);
    }
}

// ----------------------------------------------------------- pool GEMM only --
// Col-split: bid&1 selects 64 output cols (halved W-stage, 2x blocks).
__global__ __launch_bounds__(256) void k_pool(const ushort_t* __restrict__ h,
                                              const ushort_t* __restrict__ Wpk,
                                              const float* __restrict__ bias,
                                              ushort_t* __restrict__ m, int N) {
    __shared__ ushort_t Wl[8192];
    int colhalf = blockIdx.x & 1;
    int wave = (blockIdx.x >> 1) * 4 + (threadIdx.x >> 6);
    int row0 = wave * 32;
    int l = threadIdx.x & 63;
    int ar0 = row0 + (l & 15); if (ar0 >= N) ar0 = N - 1;
    int ar1 = ar0 + 16;        if (ar1 >= N) ar1 = N - 1;
    int ac = (l >> 4) * 8;
    short8 a0[4], a1[4];
#pragma unroll
    for (int s = 0; s < 4; ++s) {
        a0[s] = *(const short8*)&h[(size_t)ar0 * HD + s * 32 + ac];
        a1[s] = *(const short8*)&h[(size_t)ar1 * HD + s * 32 + ac];
    }
    stage_w_half(Wpk + colhalf * 8192, Wl, threadIdx.x);
    __syncthreads();
    if (row0 >= N) return;
    int g0 = row0 + (l & 15), g1 = g0 + 16;
    int cb0 = ((l >> 4) & 3) * 4;
#pragma unroll
    for (int t = 0; t < 4; ++t) {
        floatx4 acc0 = {0.f, 0.f, 0.f, 0.f};
        floatx4 acc1 = {0.f, 0.f, 0.f, 0.f};
#pragma unroll
        for (int s = 0; s < 4; ++s) {
            short8 w = *(const short8*)&Wl[(t * 4 + s) * 512 + l * 8];
            acc0 = __builtin_amdgcn_mfma_f32_16x16x32_bf16(w, a0[s], acc0, 0, 0, 0);
            acc1 = __builtin_amdgcn_mfma_f32_16x16x32_bf16(w, a1[s], acc1, 0, 0, 0);
        }
        int cb = (colhalf * 4 + t) * 16 + cb0;
        float4 bv = *(const float4*)&bias[cb];
        store_m(m, g0, cb, acc0, bv, N);
        store_m(m, g1, cb, acc1, bv, N);
    }
}

// ---------------------------------------------------------------- segmax -----
// [4][N+1][32] col-group layout.  Wave = 4 nodes, 16 slots x 4-lane quads
// (16 B/lane, one 64 B line per edge).  srcPad is zero-row padded: no deg
// predication at all — padding gathers hit the zero row and are idempotent
// under max (m >= 0); deg=0 nodes get exactly 0 (DGL semantics).  Only the
// rare deg>32 tail (Poisson-16, P~1e-4) reads rp/src.
__global__ __launch_bounds__(256) void k_segmax(const ushort_t* __restrict__ m,
                                                const int* __restrict__ srcPad,
                                                const int* __restrict__ src,
                                                const int* __restrict__ rp,
                                                ushort_t* __restrict__ agg, int N) {
    int cg = blockIdx.x & 3;
    int l = threadIdx.x & 63;
    int slot = l >> 2;                 // 0..15 edge slot
    int c = l & 3;                     // 16 B (4 u32) within the 64 B row-slice
    int node0 = ((blockIdx.x >> 2) * 4 + (threadIdx.x >> 6)) * 4;
    if (node0 >= N) return;
    const uint_t* __restrict__ mg = (const uint_t*)m + (size_t)cg * ((size_t)(N + 1) * 16);
    uint_t* __restrict__ aggw = (uint_t*)agg;

    int nd[4], s0[4], s1[4], bg[4], en[4];
#pragma unroll
    for (int nn = 0; nn < 4; ++nn) {
        int node = node0 + nn; if (node >= N) node = N - 1;
        nd[nn] = node;
    }
#pragma unroll
    for (int nn = 0; nn < 4; ++nn) {   // 8 coalesced srcPad loads in flight
        s0[nn] = srcPad[(size_t)nd[nn] * 32 + slot];
        s1[nn] = srcPad[(size_t)nd[nn] * 32 + 16 + slot];
    }
#pragma unroll
    for (int nn = 0; nn < 4; ++nn) {
        bg[nn] = rp[nd[nn]];
        en[nn] = rp[nd[nn] + 1];
    }
    uint4v p0[4], p1[4];
#pragma unroll
    for (int nn = 0; nn < 4; ++nn) {   // 8 independent gathers in flight
        p0[nn] = *(const uint4v*)&mg[(size_t)s0[nn] * 16 + c * 4];
        p1[nn] = *(const uint4v*)&mg[(size_t)s1[nn] * 16 + c * 4];
    }
    int b0 = slot & 1, b1 = (slot >> 1) & 1;
#pragma unroll
    for (int nn = 0; nn < 4; ++nn) {
        int node = node0 + nn;
        uint_t a0 = pkmax(p0[nn].x, p1[nn].x);
        uint_t a1 = pkmax(p0[nn].y, p1[nn].y);
        uint_t a2 = pkmax(p0[nn].z, p1[nn].z);
        uint_t a3 = pkmax(p0[nn].w, p1[nn].w);
        int deg = en[nn] - bg[nn];
        if (__builtin_expect(deg > 32, 0)) {   // rare tail
            int dm1 = deg - 1;
            for (int o = 32; o < deg; o += 16) {
                int i = o + slot; if (i > dm1) i = dm1;
                int s = src[bg[nn] + i];
                uint4v p = *(const uint4v*)&mg[(size_t)s * 16 + c * 4];
                a0 = pkmax(a0, p.x); a1 = pkmax(a1, p.y);
                a2 = pkmax(a2, p.z); a3 = pkmax(a3, p.w);
            }
        }
        // select-trick reduction over 16 slots (lane bits 2..5).
        uint_t q0 = b0 ? a2 : a0, q1 = b0 ? a3 : a1;
        uint_t r0 = b0 ? a0 : a2, r1 = b0 ? a1 : a3;
        q0 = pkmax(q0, (uint_t)__shfl_xor((int)r0, 4));
        q1 = pkmax(q1, (uint_t)__shfl_xor((int)r1, 4));
        uint_t s_ = b1 ? q1 : q0, t_ = b1 ? q0 : q1;
        s_ = pkmax(s_, (uint_t)__shfl_xor((int)t_, 8));
        s_ = pkmax(s_, (uint_t)__shfl_xor((int)s_, 16));
        s_ = pkmax(s_, (uint_t)__shfl_xor((int)s_, 32));
        if (slot < 4 && node < N)      // lane holds word c*4 + 2*b0 + b1
            __builtin_nontemporal_store(s_,
                &aggw[(size_t)node * 64 + cg * 16 + c * 4 + 2 * b0 + b1]);
    }
}

// ----------------------------------------------------------- dual GEMM -------
// out = h @ Wself + agg @ Wneigh + b; col-split like k_pool.
template <bool F32OUT>
__global__ __launch_bounds__(256) void k_dual(const ushort_t* __restrict__ h,
                                              const ushort_t* __restrict__ agg,
                                              const ushort_t* __restrict__ WsPk,
                                              const ushort_t* __restrict__ WnPk,
                                              const float* __restrict__ bias,
                                              void* __restrict__ outp, int N) {
    __shared__ ushort_t Wl[16384];                       // Ws-half | Wn-half
    int colhalf = blockIdx.x & 1;
    int wave = (blockIdx.x >> 1) * 4 + (threadIdx.x >> 6);
    int row0 = wave * 32;
    int l = threadIdx.x & 63;
    int ar0 = row0 + (l & 15); if (ar0 >= N) ar0 = N - 1;
    int ar1 = ar0 + 16;        if (ar1 >= N) ar1 = N - 1;
    int ac = (l >> 4) * 8;
    short8 ah0[4], ah1[4], ag0[4], ag1[4];
#pragma unroll
    for (int s = 0; s < 4; ++s) {
        ah0[s] = *(const short8*)&h[(size_t)ar0 * HD + s * 32 + ac];
        ah1[s] = *(const short8*)&h[(size_t)ar1 * HD + s * 32 + ac];
        ag0[s] = *(const short8*)&agg[(size_t)ar0 * HD + s * 32 + ac];
        ag1[s] = *(const short8*)&agg[(size_t)ar1 * HD + s * 32 + ac];
    }
    stage_w_half(WsPk + colhalf * 8192, Wl, threadIdx.x);
    stage_w_half(WnPk + colhalf * 8192, Wl + 8192, threadIdx.x);
    __syncthreads();
    if (row0 >= N) return;
    int g0 = row0 + (l & 15), g1 = g0 + 16;
    int cb0 = ((l >> 4) & 3) * 4;
#pragma unroll
    for (int t = 0; t < 4; ++t) {
        floatx4 acc0 = {0.f, 0.f, 0.f, 0.f};
        floatx4 acc1 = {0.f, 0.f, 0.f, 0.f};
#pragma unroll
        for (int s = 0; s < 4; ++s) {
            short8 ws = *(const short8*)&Wl[(t * 4 + s) * 512 + l * 8];
            acc0 = __builtin_amdgcn_mfma_f32_16x16x32_bf16(ws, ah0[s], acc0, 0, 0, 0);
            acc1 = __builtin_amdgcn_mfma_f32_16x16x32_bf16(ws, ah1[s], acc1, 0, 0, 0);
        }
#pragma unroll
        for (int s = 0; s < 4; ++s) {
            short8 wn = *(const short8*)&Wl[8192 + (t * 4 + s) * 512 + l * 8];
            acc0 = __builtin_amdgcn_mfma_f32_16x16x32_bf16(wn, ag0[s], acc0, 0, 0, 0);
            acc1 = __builtin_amdgcn_mfma_f32_16x16x32_bf16(wn, ag1[s], acc1, 0, 0, 0);
        }
        int cb = (colhalf * 4 + t) * 16 + cb0;
        float4 bv = *(const float4*)&bias[cb];
        if (F32OUT) {
            float* out = (float*)outp;
            if (g0 < N) {
                float4 v = make_float4(acc0[0] + bv.x, acc0[1] + bv.y,
                                       acc0[2] + bv.z, acc0[3] + bv.w);
                *(float4*)&out[(size_t)g0 * HD + cb] = v;
            }
            if (g1 < N) {
                float4 v = make_float4(acc1[0] + bv.x, acc1[1] + bv.y,
                                       acc1[2] + bv.z, acc1[3] + bv.w);
                *(float4*)&out[(size_t)g1 * HD + cb] = v;
            }
        } else {
            ushort_t* out = (ushort_t*)outp;
            store_bf16(out, g0, cb, acc0, bv, false, N);
            store_bf16(out, g1, cb, acc1, bv, false, N);
        }
    }
}

// ---------------------------------------------------------------- launch -----
extern "C" void kernel_launch(void* const* d_in, const int* in_sizes, int n_in,
                              void* d_out, int out_size, void* d_ws, size_t ws_size,
                              hipStream_t stream) {
    const int*   node_ids = (const int*)d_in[0];
    const int*   src      = (const int*)d_in[1];
    const int*   dst      = (const int*)d_in[2];
    const float* emb      = (const float*)d_in[3];
    const float* Wp1      = (const float*)d_in[4];
    const float* bp1      = (const float*)d_in[5];
    const float* Ws1      = (const float*)d_in[6];
    const float* Wn1      = (const float*)d_in[7];
    const float* b1       = (const float*)d_in[8];
    const float* Wp2      = (const float*)d_in[9];
    const float* bp2      = (const float*)d_in[10];
    const float* Ws2      = (const float*)d_in[11];
    const float* Wn2      = (const float*)d_in[12];
    const float* b2       = (const float*)d_in[13];
    float* out = (float*)d_out;

    const int N = in_sizes[0];
    const int E = in_sizes[1];

    char* ws = (char*)d_ws;
    int* rp = (int*)ws;
    size_t off = (((size_t)(N + 1) * 4) + 255) & ~(size_t)255;
    int* srcPad = (int*)(ws + off);                      // N x 32 padded lists
    off += (((size_t)N * 32 * 4) + 255) & ~(size_t)255;
    ushort_t* Wpk  = (ushort_t*)(ws + off);              // 6 x 128x128 bf16
    ushort_t* h0   = Wpk + 6 * 16384;
    ushort_t* h1   = h0 + (size_t)N * HD;
    ushort_t* bufM = h1 + (size_t)N * HD;                // [4][N+1][32] (+pad row)
    ushort_t* bufA = bufM + (size_t)(N + 1) * HD;

    const int nbR = (N + 1 + 255) / 256;
    const int nbP = 6 * 64;
    const int nbI = ((N * 32) + 255) / 256;              // srcPad init
    const int nbE = (E + 255) / 256;                     // scatter blocks
    const int nb_gemm = (N + 127) / 128;                 // 4 waves x 32 rows
    const int nb_half = nb_gemm * 2;                     // col-split GEMMs
    const int nb_seg  = ((N + 15) / 16) * 4;             // 4 col-groups

    k_prep<<<nbR + nbP + nbI, 256, 0, stream>>>(dst, E, rp, N, srcPad, bufM,
                                                Wp1, Ws1, Wn1, Wp2, Ws2, Wn2,
                                                Wpk, nbR, nbP);

    const ushort_t* Wp1k = Wpk;
    const ushort_t* Ws1k = Wpk + 16384;
    const ushort_t* Wn1k = Wpk + 2 * 16384;
    const ushort_t* Wp2k = Wpk + 3 * 16384;
    const ushort_t* Ws2k = Wpk + 4 * 16384;
    const ushort_t* Wn2k = Wpk + 5 * 16384;

    // layer 1 (gather_pool also scatters srcPad in its extra blocks)
    k_gather_pool<<<nb_gemm + nbE, 256, 0, stream>>>(node_ids, emb, Wp1k, bp1,
                                                     h0, bufM, N,
                                                     src, dst, rp, srcPad, E, nb_gemm);
    k_segmax<<<nb_seg, 256, 0, stream>>>(bufM, srcPad, src, rp, bufA, N);
    k_dual<false><<<nb_half, 256, 0, stream>>>(h0, bufA, Ws1k, Wn1k, b1, h1, N);
    // layer 2
    k_pool<<<nb_half, 256, 0, stream>>>(h1, Wp2k, bp2, bufM, N);
    k_segmax<<<nb_seg, 256, 0, stream>>>(bufM, srcPad, src, rp, bufA, N);
    k_dual<true><<<nb_half, 256, 0, stream>>>(h1, bufA, Ws2k, Wn2k, b2, out, N);
}

// Round 7
// 219.005 us; speedup vs baseline: 1.6736x; 1.0426x over previous
//
#include <hip/hip_runtime.h>

#define HD 128

typedef __attribute__((ext_vector_type(8))) short short8;   // 8 bf16
typedef __attribute__((ext_vector_type(4))) float floatx4;  // MFMA accumulator
typedef __attribute__((ext_vector_type(2))) unsigned short ushort2v;
typedef __attribute__((ext_vector_type(4))) unsigned int uint4v;

typedef unsigned short ushort_t;
typedef unsigned int uint_t;

// ---------------------------------------------------------------- helpers ----
__device__ __forceinline__ ushort_t f2b(float f) {          // fp32 -> bf16 RNE
    union { float f; uint_t u; } v; v.f = f;
    uint_t r = v.u + 0x7fff + ((v.u >> 16) & 1);
    return (ushort_t)(r >> 16);
}
__device__ __forceinline__ short8 cvt8(const float* __restrict__ p) {
    float4 u = *(const float4*)p, v = *(const float4*)(p + 4);
    short8 r;
    r[0] = (short)f2b(u.x); r[1] = (short)f2b(u.y); r[2] = (short)f2b(u.z); r[3] = (short)f2b(u.w);
    r[4] = (short)f2b(v.x); r[5] = (short)f2b(v.y); r[6] = (short)f2b(v.z); r[7] = (short)f2b(v.w);
    return r;
}
// packed bf16 max: valid because m = relu(..) >= 0, so IEEE order == u16 order.
__device__ __forceinline__ uint_t pkmax(uint_t a, uint_t b) {
    return __builtin_bit_cast(uint_t,
        __builtin_elementwise_max(__builtin_bit_cast(ushort2v, a),
                                  __builtin_bit_cast(ushort2v, b)));
}
__device__ __forceinline__ int lbound(const int* __restrict__ dst, int E, int v) {
    int lo = 0, hi = E;
    while (lo < hi) {
        int mid = (lo + hi) >> 1;
        if (dst[mid] < v) lo = mid + 1; else hi = mid;
    }
    return lo;
}

// ------------------------------------------------------------------ prep -----
// [0,nbR): rowptr.  [nbR,nbR+nbP): W-pack.  [nbR+nbP,...): srcPad init to the
// sentinel row N (zero row), plus one block zeroes bufM's pad row.  srcPad is
// then filled by a cheap scatter inside k_gather_pool (needs rp).
__global__ __launch_bounds__(256) void k_prep(const int* __restrict__ dst, int E,
                                              int* __restrict__ rp, int N,
                                              int* __restrict__ srcPad,
                                              ushort_t* __restrict__ bufM,
                                              const float* W0, const float* W1,
                                              const float* W2, const float* W3,
                                              const float* W4, const float* W5,
                                              ushort_t* __restrict__ Wpk,
                                              int nbR, int nbP) {
    int b = blockIdx.x;
    if (b < nbR) {
        int i = b * 256 + threadIdx.x;
        if (i > N) return;
        rp[i] = lbound(dst, E, i);
    } else if (b < nbR + nbP) {
        int bb = b - nbR;
        const float* Ws[6] = {W0, W1, W2, W3, W4, W5};
        int mat = bb >> 6;
        int o = ((bb & 63) << 8) + threadIdx.x;
        int j = o & 7, l = (o >> 3) & 63, s = (o >> 9) & 3, t = o >> 11;
        int k = s * 32 + ((l >> 4) & 3) * 8 + j;
        int n = t * 16 + (l & 15);
        Wpk[(size_t)mat * 16384 + o] = f2b(Ws[mat][k * HD + n]);
    } else {
        int bb = b - nbR - nbP;
        if (bb == 0 && threadIdx.x < 64) {   // zero bufM pad row (row N, 4 groups)
            uint_t* mz = (uint_t*)bufM;
            mz[(size_t)(threadIdx.x >> 4) * ((size_t)(N + 1) * 16)
               + (size_t)N * 16 + (threadIdx.x & 15)] = 0u;
        }
        int idx = bb * 256 + threadIdx.x;
        if (idx < N * 32) srcPad[idx] = N;   // sentinel: points at zero row
    }
}

// ---------------------------------------------------------- W -> LDS stage ---
__device__ __forceinline__ void stage_w(const ushort_t* __restrict__ g,
                                        ushort_t* l, int tid) {
#pragma unroll
    for (int i = 0; i < 8; ++i) {
        int off = i * 2048 + tid * 8;
        *(short8*)&l[off] = *(const short8*)&g[off];
    }
}
__device__ __forceinline__ void stage_w_half(const ushort_t* __restrict__ g,
                                             ushort_t* l, int tid) {
#pragma unroll
    for (int i = 0; i < 4; ++i) {
        int off = i * 2048 + tid * 8;
        *(short8*)&l[off] = *(const short8*)&g[off];
    }
}

// --------------------------------------------------------------- epilogue ----
// D = mfma(Wfrag, hfrag): lane&15 = h-row, quad*4+reg = output col within tile.
__device__ __forceinline__ void store_bf16(ushort_t* __restrict__ m, int row,
                                           int colbase, const floatx4& acc,
                                           const float4& bv, bool relu, int N) {
    if (row >= N) return;
    float v0 = acc[0] + bv.x, v1 = acc[1] + bv.y, v2 = acc[2] + bv.z, v3 = acc[3] + bv.w;
    if (relu) { v0 = fmaxf(v0, 0.f); v1 = fmaxf(v1, 0.f); v2 = fmaxf(v2, 0.f); v3 = fmaxf(v3, 0.f); }
    uint2 o; o.x = (uint_t)f2b(v0) | ((uint_t)f2b(v1) << 16);
    o.y = (uint_t)f2b(v2) | ((uint_t)f2b(v3) << 16);
    *(uint2*)&m[(size_t)row * HD + colbase] = o;
}

// m is col-group-major [4 groups][N+1 rows][32 cols] bf16; row N is the zero
// pad row.  One group slice ~3.2 MB (fits a 4 MiB XCD L2); one row-slice =
// exactly one 64 B line.
__device__ __forceinline__ void store_m(ushort_t* __restrict__ m, int row,
                                        int colbase, const floatx4& acc,
                                        const float4& bv, int N) {
    if (row >= N) return;
    float v0 = fmaxf(acc[0] + bv.x, 0.f), v1 = fmaxf(acc[1] + bv.y, 0.f);
    float v2 = fmaxf(acc[2] + bv.z, 0.f), v3 = fmaxf(acc[3] + bv.w, 0.f);
    uint2 o; o.x = (uint_t)f2b(v0) | ((uint_t)f2b(v1) << 16);
    o.y = (uint_t)f2b(v2) | ((uint_t)f2b(v3) << 16);
    size_t addr = (size_t)(colbase >> 5) * ((size_t)(N + 1) * 32)
                + (size_t)row * 32 + (colbase & 31);
    *(uint2*)&m[addr] = o;
}

// ------------------------------------------------------ gather + pool GEMM ---
// Blocks [0,nb_gemm): h0 = bf16(emb[ids]); m = relu(h0 @ Wp + b).
// Blocks [nb_gemm,..): srcPad scatter — slot j = e - rp[dst[e]], j<32.
__global__ __launch_bounds__(256) void k_gather_pool(const int* __restrict__ ids,
                                                     const float* __restrict__ emb,
                                                     const ushort_t* __restrict__ Wpk,
                                                     const float* __restrict__ bias,
                                                     ushort_t* __restrict__ h0,
                                                     ushort_t* __restrict__ m, int N,
                                                     const int* __restrict__ src,
                                                     const int* __restrict__ dst,
                                                     const int* __restrict__ rp,
                                                     int* __restrict__ srcPad,
                                                     int E, int nb_gemm) {
    if ((int)blockIdx.x >= nb_gemm) {        // ---- scatter region ----
        int e = (blockIdx.x - nb_gemm) * 256 + threadIdx.x;
        if (e < E) {
            int node = dst[e];
            int j = e - rp[node];
            if (j < 32) srcPad[(size_t)node * 32 + j] = src[e];
        }
        return;
    }
    __shared__ ushort_t Wl[16384];
    int wave = blockIdx.x * 4 + (threadIdx.x >> 6);
    int row0 = wave * 32;
    int l = threadIdx.x & 63;
    int ar0 = row0 + (l & 15); if (ar0 >= N) ar0 = N - 1;
    int ar1 = ar0 + 16;        if (ar1 >= N) ar1 = N - 1;
    int ac = (l >> 4) * 8;
    int id0 = ids[ar0], id1 = ids[ar1];
    short8 a0[4], a1[4];
#pragma unroll
    for (int s = 0; s < 4; ++s) {
        a0[s] = cvt8(&emb[(size_t)id0 * HD + s * 32 + ac]);
        a1[s] = cvt8(&emb[(size_t)id1 * HD + s * 32 + ac]);
    }
    stage_w(Wpk, Wl, threadIdx.x);
    __syncthreads();
    if (row0 >= N) return;
#pragma unroll
    for (int s = 0; s < 4; ++s) {
        *(short8*)&h0[(size_t)ar0 * HD + s * 32 + ac] = a0[s];
        *(short8*)&h0[(size_t)ar1 * HD + s * 32 + ac] = a1[s];
    }
    int g0 = row0 + (l & 15), g1 = g0 + 16;
    int cb0 = ((l >> 4) & 3) * 4;
#pragma unroll
    for (int t = 0; t < 8; ++t) {
        floatx4 acc0 = {0.f, 0.f, 0.f, 0.f};
        floatx4 acc1 = {0.f, 0.f, 0.f, 0.f};
#pragma unroll
        for (int s = 0; s < 4; ++s) {
            short8 w = *(const short8*)&Wl[(t * 4 + s) * 512 + l * 8];
            acc0 = __builtin_amdgcn_mfma_f32_16x16x32_bf16(w, a0[s], acc0, 0, 0, 0);
            acc1 = __builtin_amdgcn_mfma_f32_16x16x32_bf16(w, a1[s], acc1, 0, 0, 0);
        }
        int cb = t * 16 + cb0;
        float4 bv = *(const float4*)&bias[cb];
        store_m(m, g0, cb, acc0, bv, N);
        store_m(m, g1, cb, acc1, bv, N);
    }
}

// ---------------------------------------------------------------- segmax -----
// [4][N+1][32] col-group layout.  Wave = 4 nodes, 16 slots x 4-lane quads
// (16 B/lane, one 64 B line per edge).  srcPad is zero-row padded: no deg
// predication; padding gathers hit the zero row (idempotent under max since
// m >= 0); deg=0 nodes get exactly 0 (DGL semantics).  Only the rare deg>32
// tail (Poisson-16, P~1e-4) reads rp/src.
__global__ __launch_bounds__(256) void k_segmax(const ushort_t* __restrict__ m,
                                                const int* __restrict__ srcPad,
                                                const int* __restrict__ src,
                                                const int* __restrict__ rp,
                                                ushort_t* __restrict__ agg, int N) {
    int cg = blockIdx.x & 3;
    int l = threadIdx.x & 63;
    int slot = l >> 2;                 // 0..15 edge slot
    int c = l & 3;                     // 16 B (4 u32) within the 64 B row-slice
    int node0 = ((blockIdx.x >> 2) * 4 + (threadIdx.x >> 6)) * 4;
    if (node0 >= N) return;
    const uint_t* __restrict__ mg = (const uint_t*)m + (size_t)cg * ((size_t)(N + 1) * 16);
    uint_t* __restrict__ aggw = (uint_t*)agg;

    int nd[4], s0[4], s1[4], bg[4], en[4];
#pragma unroll
    for (int nn = 0; nn < 4; ++nn) {
        int node = node0 + nn; if (node >= N) node = N - 1;
        nd[nn] = node;
    }
#pragma unroll
    for (int nn = 0; nn < 4; ++nn) {   // 8 coalesced srcPad loads in flight
        s0[nn] = srcPad[(size_t)nd[nn] * 32 + slot];
        s1[nn] = srcPad[(size_t)nd[nn] * 32 + 16 + slot];
    }
#pragma unroll
    for (int nn = 0; nn < 4; ++nn) {
        bg[nn] = rp[nd[nn]];
        en[nn] = rp[nd[nn] + 1];
    }
    uint4v p0[4], p1[4];
#pragma unroll
    for (int nn = 0; nn < 4; ++nn) {   // 8 independent gathers in flight
        p0[nn] = *(const uint4v*)&mg[(size_t)s0[nn] * 16 + c * 4];
        p1[nn] = *(const uint4v*)&mg[(size_t)s1[nn] * 16 + c * 4];
    }
    int b0 = slot & 1, b1 = (slot >> 1) & 1;
#pragma unroll
    for (int nn = 0; nn < 4; ++nn) {
        int node = node0 + nn;
        uint_t a0 = pkmax(p0[nn].x, p1[nn].x);
        uint_t a1 = pkmax(p0[nn].y, p1[nn].y);
        uint_t a2 = pkmax(p0[nn].z, p1[nn].z);
        uint_t a3 = pkmax(p0[nn].w, p1[nn].w);
        int deg = en[nn] - bg[nn];
        if (__builtin_expect(deg > 32, 0)) {   // rare tail
            int dm1 = deg - 1;
            for (int o = 32; o < deg; o += 16) {
                int i = o + slot; if (i > dm1) i = dm1;
                int s = src[bg[nn] + i];
                uint4v p = *(const uint4v*)&mg[(size_t)s * 16 + c * 4];
                a0 = pkmax(a0, p.x); a1 = pkmax(a1, p.y);
                a2 = pkmax(a2, p.z); a3 = pkmax(a3, p.w);
            }
        }
        // select-trick reduction over 16 slots (lane bits 2..5).
        uint_t q0 = b0 ? a2 : a0, q1 = b0 ? a3 : a1;
        uint_t r0 = b0 ? a0 : a2, r1 = b0 ? a1 : a3;
        q0 = pkmax(q0, (uint_t)__shfl_xor((int)r0, 4));
        q1 = pkmax(q1, (uint_t)__shfl_xor((int)r1, 4));
        uint_t s_ = b1 ? q1 : q0, t_ = b1 ? q0 : q1;
        s_ = pkmax(s_, (uint_t)__shfl_xor((int)t_, 8));
        s_ = pkmax(s_, (uint_t)__shfl_xor((int)s_, 16));
        s_ = pkmax(s_, (uint_t)__shfl_xor((int)s_, 32));
        if (slot < 4 && node < N)      // lane holds word c*4 + 2*b0 + b1
            __builtin_nontemporal_store(s_,
                &aggw[(size_t)node * 64 + cg * 16 + c * 4 + 2 * b0 + b1]);
    }
}

// ------------------------------------------- fused dual-1 + pool-2 kernel ----
// h1 = h0 @ Ws1 + agg @ Wn1 + b1  (written to global for layer-2 dual), and
// m2 = relu(h1 @ Wp2 + bp2) (written to bufM) — pool-2 is row-local, so the
// block round-trips its 128x128 h1 tile through a swizzled LDS h-tile
// (C-frag layout != A-frag layout).  W staged in temporal col-halves: LDS =
// 32 KB W + 32 KB h-tile = 64 KB (2 blocks/CU).  Same bf16 h1 values feed
// pool-2 as before (bit-identical to the separate k_pool).
// All waves execute all barriers; global stores are predicated (no early ret).
__global__ __launch_bounds__(256) void k_dual_pool(const ushort_t* __restrict__ h,
                                                   const ushort_t* __restrict__ agg,
                                                   const ushort_t* __restrict__ WsPk,
                                                   const ushort_t* __restrict__ WnPk,
                                                   const ushort_t* __restrict__ WpPk,
                                                   const float* __restrict__ bias1,
                                                   const float* __restrict__ biasP,
                                                   ushort_t* __restrict__ h1out,
                                                   ushort_t* __restrict__ m2, int N) {
    __shared__ ushort_t Wl[16384];     // 32 KB: current W col-half (Ws|Wn or Wp2)
    __shared__ ushort_t Ht[16384];     // 32 KB: 4 waves x 32 rows x 128 cols bf16
    int wave = threadIdx.x >> 6;
    int row0 = blockIdx.x * 128 + wave * 32;
    int l = threadIdx.x & 63;
    int ar0 = row0 + (l & 15); if (ar0 >= N) ar0 = N - 1;
    int ar1 = ar0 + 16;        if (ar1 >= N) ar1 = N - 1;
    int ac = (l >> 4) * 8;
    short8 ah0[4], ah1[4], ag0[4], ag1[4];
#pragma unroll
    for (int s = 0; s < 4; ++s) {
        ah0[s] = *(const short8*)&h[(size_t)ar0 * HD + s * 32 + ac];
        ah1[s] = *(const short8*)&h[(size_t)ar1 * HD + s * 32 + ac];
        ag0[s] = *(const short8*)&agg[(size_t)ar0 * HD + s * 32 + ac];
        ag1[s] = *(const short8*)&agg[(size_t)ar1 * HD + s * 32 + ac];
    }
    int g0 = row0 + (l & 15), g1 = g0 + 16;
    int cb0 = ((l >> 4) & 3) * 4;
    char* ht = (char*)(Ht + wave * 4096);          // 32 rows x 128 cols bf16
    int trow0 = l & 15, trow1 = trow0 + 16;
    int swz0 = (trow0 & 7) << 4, swz1 = swz0;      // (trow&7) identical for +16

    // ---- dual GEMM in two W col-halves ----
#pragma unroll
    for (int half = 0; half < 2; ++half) {
        if (half == 1) __syncthreads();            // done reading half 0
        stage_w_half(WsPk + half * 8192, Wl, threadIdx.x);
        stage_w_half(WnPk + half * 8192, Wl + 8192, threadIdx.x);
        __syncthreads();
#pragma unroll
        for (int t = 0; t < 4; ++t) {
            floatx4 acc0 = {0.f, 0.f, 0.f, 0.f};
            floatx4 acc1 = {0.f, 0.f, 0.f, 0.f};
#pragma unroll
            for (int s = 0; s < 4; ++s) {
                short8 ws = *(const short8*)&Wl[(t * 4 + s) * 512 + l * 8];
                acc0 = __builtin_amdgcn_mfma_f32_16x16x32_bf16(ws, ah0[s], acc0, 0, 0, 0);
                acc1 = __builtin_amdgcn_mfma_f32_16x16x32_bf16(ws, ah1[s], acc1, 0, 0, 0);
            }
#pragma unroll
            for (int s = 0; s < 4; ++s) {
                short8 wn = *(const short8*)&Wl[8192 + (t * 4 + s) * 512 + l * 8];
                acc0 = __builtin_amdgcn_mfma_f32_16x16x32_bf16(wn, ag0[s], acc0, 0, 0, 0);
                acc1 = __builtin_amdgcn_mfma_f32_16x16x32_bf16(wn, ag1[s], acc1, 0, 0, 0);
            }
            int cb = (half * 4 + t) * 16 + cb0;
            float4 bv = *(const float4*)&bias1[cb];
            uint2 o0, o1;
            o0.x = (uint_t)f2b(acc0[0] + bv.x) | ((uint_t)f2b(acc0[1] + bv.y) << 16);
            o0.y = (uint_t)f2b(acc0[2] + bv.z) | ((uint_t)f2b(acc0[3] + bv.w) << 16);
            o1.x = (uint_t)f2b(acc1[0] + bv.x) | ((uint_t)f2b(acc1[1] + bv.y) << 16);
            o1.y = (uint_t)f2b(acc1[2] + bv.z) | ((uint_t)f2b(acc1[3] + bv.w) << 16);
            if (g0 < N) *(uint2*)&h1out[(size_t)g0 * HD + cb] = o0;
            if (g1 < N) *(uint2*)&h1out[(size_t)g1 * HD + cb] = o1;
            *(uint2*)(ht + ((trow0 * 256 + cb * 2) ^ swz0)) = o0;
            *(uint2*)(ht + ((trow1 * 256 + cb * 2) ^ swz1)) = o1;
        }
    }

    // ---- pool A-fragments from own wave's h-tile (same-wave RAW; compiler
    //      inserts the lgkmcnt wait) ----
    short8 pa0[4], pa1[4];
#pragma unroll
    for (int s = 0; s < 4; ++s) {
        int colb = (s * 32 + (l >> 4) * 8) * 2;
        pa0[s] = *(const short8*)(ht + ((trow0 * 256 + colb) ^ swz0));
        pa1[s] = *(const short8*)(ht + ((trow1 * 256 + colb) ^ swz1));
    }

    // ---- pool GEMM in two W col-halves ----
#pragma unroll
    for (int half = 0; half < 2; ++half) {
        __syncthreads();                           // done reading previous Wl
        stage_w_half(WpPk + half * 8192, Wl, threadIdx.x);
        __syncthreads();
#pragma unroll
        for (int t = 0; t < 4; ++t) {
            floatx4 acc0 = {0.f, 0.f, 0.f, 0.f};
            floatx4 acc1 = {0.f, 0.f, 0.f, 0.f};
#pragma unroll
            for (int s = 0; s < 4; ++s) {
                short8 w = *(const short8*)&Wl[(t * 4 + s) * 512 + l * 8];
                acc0 = __builtin_amdgcn_mfma_f32_16x16x32_bf16(w, pa0[s], acc0, 0, 0, 0);
                acc1 = __builtin_amdgcn_mfma_f32_16x16x32_bf16(w, pa1[s], acc1, 0, 0, 0);
            }
            int cb = (half * 4 + t) * 16 + cb0;
            float4 bv = *(const float4*)&biasP[cb];
            store_m(m2, g0, cb, acc0, bv, N);
            store_m(m2, g1, cb, acc1, bv, N);
        }
    }
}

// ----------------------------------------------------------- dual GEMM -------
// out = h @ Wself + agg @ Wneigh + b; col-split (layer 2, f32 out).
template <bool F32OUT>
__global__ __launch_bounds__(256) void k_dual(const ushort_t* __restrict__ h,
                                              const ushort_t* __restrict__ agg,
                                              const ushort_t* __restrict__ WsPk,
                                              const ushort_t* __restrict__ WnPk,
                                              const float* __restrict__ bias,
                                              void* __restrict__ outp, int N) {
    __shared__ ushort_t Wl[16384];                       // Ws-half | Wn-half
    int colhalf = blockIdx.x & 1;
    int wave = (blockIdx.x >> 1) * 4 + (threadIdx.x >> 6);
    int row0 = wave * 32;
    int l = threadIdx.x & 63;
    int ar0 = row0 + (l & 15); if (ar0 >= N) ar0 = N - 1;
    int ar1 = ar0 + 16;        if (ar1 >= N) ar1 = N - 1;
    int ac = (l >> 4) * 8;
    short8 ah0[4], ah1[4], ag0[4], ag1[4];
#pragma unroll
    for (int s = 0; s < 4; ++s) {
        ah0[s] = *(const short8*)&h[(size_t)ar0 * HD + s * 32 + ac];
        ah1[s] = *(const short8*)&h[(size_t)ar1 * HD + s * 32 + ac];
        ag0[s] = *(const short8*)&agg[(size_t)ar0 * HD + s * 32 + ac];
        ag1[s] = *(const short8*)&agg[(size_t)ar1 * HD + s * 32 + ac];
    }
    stage_w_half(WsPk + colhalf * 8192, Wl, threadIdx.x);
    stage_w_half(WnPk + colhalf * 8192, Wl + 8192, threadIdx.x);
    __syncthreads();
    if (row0 >= N) return;
    int g0 = row0 + (l & 15), g1 = g0 + 16;
    int cb0 = ((l >> 4) & 3) * 4;
#pragma unroll
    for (int t = 0; t < 4; ++t) {
        floatx4 acc0 = {0.f, 0.f, 0.f, 0.f};
        floatx4 acc1 = {0.f, 0.f, 0.f, 0.f};
#pragma unroll
        for (int s = 0; s < 4; ++s) {
            short8 ws = *(const short8*)&Wl[(t * 4 + s) * 512 + l * 8];
            acc0 = __builtin_amdgcn_mfma_f32_16x16x32_bf16(ws, ah0[s], acc0, 0, 0, 0);
            acc1 = __builtin_amdgcn_mfma_f32_16x16x32_bf16(ws, ah1[s], acc1, 0, 0, 0);
        }
#pragma unroll
        for (int s = 0; s < 4; ++s) {
            short8 wn = *(const short8*)&Wl[8192 + (t * 4 + s) * 512 + l * 8];
            acc0 = __builtin_amdgcn_mfma_f32_16x16x32_bf16(wn, ag0[s], acc0, 0, 0, 0);
            acc1 = __builtin_amdgcn_mfma_f32_16x16x32_bf16(wn, ag1[s], acc1, 0, 0, 0);
        }
        int cb = (colhalf * 4 + t) * 16 + cb0;
        float4 bv = *(const float4*)&bias[cb];
        if (F32OUT) {
            float* out = (float*)outp;
            if (g0 < N) {
                float4 v = make_float4(acc0[0] + bv.x, acc0[1] + bv.y,
                                       acc0[2] + bv.z, acc0[3] + bv.w);
                *(float4*)&out[(size_t)g0 * HD + cb] = v;
            }
            if (g1 < N) {
                float4 v = make_float4(acc1[0] + bv.x, acc1[1] + bv.y,
                                       acc1[2] + bv.z, acc1[3] + bv.w);
                *(float4*)&out[(size_t)g1 * HD + cb] = v;
            }
        } else {
            ushort_t* out = (ushort_t*)outp;
            store_bf16(out, g0, cb, acc0, bv, false, N);
            store_bf16(out, g1, cb, acc1, bv, false, N);
        }
    }
}

// ---------------------------------------------------------------- launch -----
extern "C" void kernel_launch(void* const* d_in, const int* in_sizes, int n_in,
                              void* d_out, int out_size, void* d_ws, size_t ws_size,
                              hipStream_t stream) {
    const int*   node_ids = (const int*)d_in[0];
    const int*   src      = (const int*)d_in[1];
    const int*   dst      = (const int*)d_in[2];
    const float* emb      = (const float*)d_in[3];
    const float* Wp1      = (const float*)d_in[4];
    const float* bp1      = (const float*)d_in[5];
    const float* Ws1      = (const float*)d_in[6];
    const float* Wn1      = (const float*)d_in[7];
    const float* b1       = (const float*)d_in[8];
    const float* Wp2      = (const float*)d_in[9];
    const float* bp2      = (const float*)d_in[10];
    const float* Ws2      = (const float*)d_in[11];
    const float* Wn2      = (const float*)d_in[12];
    const float* b2       = (const float*)d_in[13];
    float* out = (float*)d_out;

    const int N = in_sizes[0];
    const int E = in_sizes[1];

    char* ws = (char*)d_ws;
    int* rp = (int*)ws;
    size_t off = (((size_t)(N + 1) * 4) + 255) & ~(size_t)255;
    int* srcPad = (int*)(ws + off);                      // N x 32 padded lists
    off += (((size_t)N * 32 * 4) + 255) & ~(size_t)255;
    ushort_t* Wpk  = (ushort_t*)(ws + off);              // 6 x 128x128 bf16
    ushort_t* h0   = Wpk + 6 * 16384;
    ushort_t* h1   = h0 + (size_t)N * HD;
    ushort_t* bufM = h1 + (size_t)N * HD;                // [4][N+1][32] (+pad row)
    ushort_t* bufA = bufM + (size_t)(N + 1) * HD;

    const int nbR = (N + 1 + 255) / 256;
    const int nbP = 6 * 64;
    const int nbI = ((N * 32) + 255) / 256;              // srcPad init
    const int nbE = (E + 255) / 256;                     // scatter blocks
    const int nb_gemm = (N + 127) / 128;                 // 4 waves x 32 rows
    const int nb_half = nb_gemm * 2;                     // col-split GEMMs
    const int nb_seg  = ((N + 15) / 16) * 4;             // 4 col-groups

    k_prep<<<nbR + nbP + nbI, 256, 0, stream>>>(dst, E, rp, N, srcPad, bufM,
                                                Wp1, Ws1, Wn1, Wp2, Ws2, Wn2,
                                                Wpk, nbR, nbP);

    const ushort_t* Wp1k = Wpk;
    const ushort_t* Ws1k = Wpk + 16384;
    const ushort_t* Wn1k = Wpk + 2 * 16384;
    const ushort_t* Wp2k = Wpk + 3 * 16384;
    const ushort_t* Ws2k = Wpk + 4 * 16384;
    const ushort_t* Wn2k = Wpk + 5 * 16384;

    // layer 1 (gather_pool also scatters srcPad in its extra blocks)
    k_gather_pool<<<nb_gemm + nbE, 256, 0, stream>>>(node_ids, emb, Wp1k, bp1,
                                                     h0, bufM, N,
                                                     src, dst, rp, srcPad, E, nb_gemm);
    k_segmax<<<nb_seg, 256, 0, stream>>>(bufM, srcPad, src, rp, bufA, N);
    // fused: dual-1 (h1) + pool-2 (bufM)
    k_dual_pool<<<nb_gemm, 256, 0, stream>>>(h0, bufA, Ws1k, Wn1k, Wp2k,
                                             b1, bp2, h1, bufM, N);
    // layer 2
    k_segmax<<<nb_seg, 256, 0, stream>>>(bufM, srcPad, src, rp, bufA, N);
    k_dual<true><<<nb_half, 256, 0, stream>>>(h1, bufA, Ws2k, Wn2k, b2, out, N);
}